// Round 13
// baseline (271.051 us; speedup 1.0000x reference)
//
#include <hip/hip_runtime.h>
#include <hip/hip_bf16.h>

#define B_SZ    32768
#define LAT     1024
#define EMB     32
#define ZCB     8192
#define NSPL    8                /* code splits for kdistM: 1024 codes each */
#define CPS     (ZCB / NSPL)     /* 1024 */
#define RESC_CAP 32768
#define EPS_MARGIN 2e-4f

/* d_out float offsets: out, loss, enc, cb, idx, ze */
#define OFF_LOSS  ((size_t)B_SZ * LAT)
#define OFF_ENC   (OFF_LOSS + 1)
#define OFF_CB    (OFF_LOSS + 2)
#define OFF_IDX   (OFF_LOSS + 3)
#define OFF_ZE    (OFF_IDX + B_SZ)

/* ws float offsets */
#define WS_PB1    0                       /* NSPL*B = 262144 */
#define WS_PB2    262144
#define WS_PL15   524288                  /* 262144 ints */
#define WS_ZEA    2097152                 /* 1048576 */
#define WS_ZNPK   3145728                 /* B*64 shorts = 1048576 floats */
#define WS_WPK    4194304                 /* Z*64 shorts = 262144 floats */
#define WS_IDXT   4456448                 /* 32768 ints */
#define WS_CNT    4489216                 /* 1 int */
#define WS_LIST   4489217                 /* 32768 ints */
#define WS_LPART  4521985                 /* 256 */

typedef float  f32x4  __attribute__((ext_vector_type(4)));
typedef short  short8 __attribute__((ext_vector_type(8)));
typedef short  s4v    __attribute__((ext_vector_type(4)));

__device__ __forceinline__ unsigned short f2bf(float x) {
    unsigned u = __float_as_uint(x);
    u += 0x7FFF + ((u >> 16) & 1);            /* round-to-nearest-even */
    return (unsigned short)(u >> 16);
}
__device__ __forceinline__ float bf2f(unsigned short h) {
    return __uint_as_float(((unsigned)h) << 16);
}

/* ---------------- codebook: normalize + split-bf16 pack; zeroes cnt ---------------- */
__global__ __launch_bounds__(256) void knorm(const float* __restrict__ cb,
                                             short* __restrict__ wpk,
                                             int* __restrict__ cnt) {
    if (blockIdx.x == 0 && threadIdx.x == 0 && threadIdx.y == 0) *cnt = 0;
    int e = threadIdx.x;
    int r = threadIdx.y;
    int row = blockIdx.x * 8 + r;
    float v = cb[row * EMB + e];
    float s = v * v;
    #pragma unroll
    for (int m = 16; m >= 1; m >>= 1) s += __shfl_xor(s, m, 64);
    float n = fmaxf(sqrtf(s), 1e-12f);
    float w = v / n;
    unsigned short h = f2bf(w);
    unsigned short l = f2bf(w - bf2f(h));
    wpk[row * 64 + e]      = (short)h;
    wpk[row * 64 + 32 + e] = (short)l;
}

/* ------- kzeF: full-K ze GEMM + bias + norm + pack (fused kze2+kprep) -------
   32 rows/block, 8 lanes/row, 4 emb/lane. TWO accumulators (chunks 0-7, 8-15)
   summed as (acc0+acc1)+bias -> per-element fp32 chain BIT-IDENTICAL to the
   verified R11/R12 two-split pipeline. Norm-reduce regrouping only perturbs
   znpk (bf16), which the margin+rescore machinery absorbs (fp32 scores
   come from ze_a). */
#define KZB 64
#define KZS 68
__global__ __launch_bounds__(256) void kzeF(const float* __restrict__ z_e,
                                            const float* __restrict__ in_w,
                                            const float* __restrict__ in_b,
                                            float* __restrict__ ze_out,
                                            float* __restrict__ ze_a,
                                            short* __restrict__ znpk) {
    __shared__ float zs[32 * KZS];   /* 8.7 KB */
    __shared__ float wt[KZB * 32];   /* 8 KB */
    int tid = threadIdx.x;
    size_t row0 = (size_t)blockIdx.x * 32;
    int rs = tid >> 3;        /* 0..31: row */
    int eg = tid & 7;         /* 0..7 */
    int E  = eg * 4;

    float acc0[4], acc1[4];
    #pragma unroll
    for (int j = 0; j < 4; ++j) { acc0[j] = 0.f; acc1[j] = 0.f; }

#define ZCHUNKS(CLO, CHI, ACC)                                                  \
    for (int c = (CLO); c < (CHI); ++c) {                                       \
        int kb = c * KZB;                                                       \
        __syncthreads();                                                        \
        _Pragma("unroll")                                                       \
        for (int i = 0; i < 2; ++i) {                                           \
            int t = tid + i * 256;                                              \
            int r = t >> 4, c4 = t & 15;                                        \
            float4 v = *(const float4*)(z_e + (row0 + r) * LAT + kb + c4 * 4);  \
            *(float4*)&zs[r * KZS + c4 * 4] = v;                                \
        }                                                                       \
        _Pragma("unroll")                                                       \
        for (int i = 0; i < 2; ++i) {                                           \
            int t = tid + i * 256;                                              \
            int e = t >> 4, k4 = t & 15;                                        \
            float4 v = *(const float4*)(in_w + (size_t)e * LAT + kb + k4 * 4);  \
            float vv[4] = {v.x, v.y, v.z, v.w};                                 \
            _Pragma("unroll")                                                   \
            for (int j = 0; j < 4; ++j) {                                       \
                int k = k4 * 4 + j;                                             \
                wt[k * 32 + (e ^ ((k & 7) << 2))] = vv[j];                      \
            }                                                                   \
        }                                                                       \
        __syncthreads();                                                        \
        _Pragma("unroll 4")                                                     \
        for (int kq = 0; kq < KZB / 4; ++kq) {                                  \
            int k0 = kq * 4;                                                    \
            float4 za = *(const float4*)&zs[rs * KZS + k0];                     \
            float zav[4] = {za.x, za.y, za.z, za.w};                            \
            _Pragma("unroll")                                                   \
            for (int i = 0; i < 4; ++i) {                                       \
                int k = k0 + i;                                                 \
                int sw = (k & 7) << 2;                                          \
                float4 w0 = *(const float4*)&wt[k * 32 + (E ^ sw)];             \
                float wa[4] = {w0.x, w0.y, w0.z, w0.w};                         \
                _Pragma("unroll")                                               \
                for (int j = 0; j < 4; ++j)                                     \
                    ACC[j] = fmaf(zav[i], wa[j], ACC[j]);                       \
            }                                                                   \
        }                                                                       \
    }

    ZCHUNKS(0, 8, acc0)
    ZCHUNKS(8, 16, acc1)
#undef ZCHUNKS

    float4 b4 = *(const float4*)(in_b + E);
    float bias[4] = {b4.x, b4.y, b4.z, b4.w};
    float v[4];
    #pragma unroll
    for (int j = 0; j < 4; ++j) v[j] = (acc0[j] + acc1[j]) + bias[j];
    float nn = 0.f;
    #pragma unroll
    for (int j = 0; j < 4; ++j) nn = fmaf(v[j], v[j], nn);
    nn += __shfl_xor(nn, 1, 64);
    nn += __shfl_xor(nn, 2, 64);
    nn += __shfl_xor(nn, 4, 64);
    float n = fmaxf(sqrtf(nn), 1e-12f);

    size_t row = row0 + rs;
    *(float4*)(ze_a + row * 32 + E) = make_float4(v[0], v[1], v[2], v[3]);
    #pragma unroll
    for (int j = 0; j < 4; ++j) ze_out[row * 32 + E + j] = v[j];

    s4v hv, lv;
    #pragma unroll
    for (int j = 0; j < 4; ++j) {
        float x = v[j] / n;
        unsigned short h = f2bf(x);
        unsigned short lo = f2bf(x - bf2f(h));
        hv[j] = (short)h;
        lv[j] = (short)lo;
    }
    *(s4v*)(znpk + row * 64 + E)      = hv;
    *(s4v*)(znpk + row * 64 + 32 + E) = lv;
}

/* ---------------- MFMA distance: LDS-staged codes (verified R12) ---------------- */
__global__ __launch_bounds__(256) void kdistM(const short* __restrict__ znpk,
                                              const short* __restrict__ wpk,
                                              float* __restrict__ pb1,
                                              float* __restrict__ pb2,
                                              int*   __restrict__ pl15) {
    __shared__ short wch[2][128 * 64];   /* 2 x 16 KB */
    int tid = threadIdx.x;
    int wave = tid >> 6, l = tid & 63;
    int l15 = l & 15, g = l >> 4;
    size_t rowbase = (size_t)blockIdx.x * 256 + wave * 64;
    int s = blockIdx.y;

    short8 zh[4], zl[4];
    #pragma unroll
    for (int rt = 0; rt < 4; ++rt) {
        const short8* p = (const short8*)(znpk + (rowbase + rt * 16 + l15) * 64 + g * 8);
        zh[rt] = p[0];
        zl[rt] = p[4];
    }
    f32x4 zero4 = {0.f, 0.f, 0.f, 0.f};
    float bb1[16];
    #pragma unroll
    for (int i = 0; i < 16; ++i) bb1[i] = -1e30f;

    int sw = (l15 & 7) << 4;
    int bhoff = ((g * 16) ^ sw) >> 1;
    int bloff = ((64 + g * 16) ^ sw) >> 1;

    const short* wsrc = wpk + (size_t)s * CPS * 64;

    #pragma unroll
    for (int i = 0; i < 4; ++i) {
        int t = tid + i * 256;
        int code = t >> 3, slot = t & 7;
        short8 v = *(const short8*)(wsrc + (size_t)code * 64 + slot * 8);
        int doff = (slot * 16) ^ ((code & 7) << 4);
        *(short8*)&wch[0][code * 64 + (doff >> 1)] = v;
    }
    __syncthreads();

    for (int c = 0; c < 8; ++c) {
        if (c + 1 < 8) {
            const short* src = wsrc + (size_t)(c + 1) * 128 * 64;
            #pragma unroll
            for (int i = 0; i < 4; ++i) {
                int t = tid + i * 256;
                int code = t >> 3, slot = t & 7;
                short8 v = *(const short8*)(src + (size_t)code * 64 + slot * 8);
                int doff = (slot * 16) ^ ((code & 7) << 4);
                *(short8*)&wch[(c + 1) & 1][code * 64 + (doff >> 1)] = v;
            }
        }
        const short* W = &wch[c & 1][0];
        #pragma unroll
        for (int tt = 0; tt < 8; ++tt) {
            const short* rowp = W + (tt * 16 + l15) * 64;
            short8 bh = *(const short8*)(rowp + bhoff);
            short8 bl = *(const short8*)(rowp + bloff);
            #pragma unroll
            for (int rt = 0; rt < 4; ++rt) {
                f32x4 acc = __builtin_amdgcn_mfma_f32_16x16x32_bf16(zh[rt], bh, zero4, 0, 0, 0);
                acc = __builtin_amdgcn_mfma_f32_16x16x32_bf16(zl[rt], bh, acc, 0, 0, 0);
                acc = __builtin_amdgcn_mfma_f32_16x16x32_bf16(zh[rt], bl, acc, 0, 0, 0);
                #pragma unroll
                for (int r = 0; r < 4; ++r) {
                    int slot = rt * 4 + r;
                    bb1[slot] = fmaxf(bb1[slot], acc[r]);
                }
            }
        }
        __syncthreads();
    }
    #pragma unroll
    for (int slot = 0; slot < 16; ++slot) {
        float B1 = bb1[slot], B2 = -1e30f;
        int ID = l15;
        #pragma unroll
        for (int m = 1; m <= 8; m <<= 1) {
            float ob1 = __shfl_xor(B1, m, 64);
            float ob2 = __shfl_xor(B2, m, 64);
            int   oid = __shfl_xor(ID, m, 64);
            float mn = fminf(B1, ob1);
            B2 = fmaxf(fmaxf(B2, ob2), mn);
            bool take = (ob1 > B1) || (ob1 == B1 && oid < ID);
            B1 = take ? ob1 : B1;
            ID = take ? oid : ID;
        }
        if (l15 == 0) {
            size_t row = rowbase + (size_t)(slot >> 2) * 16 + g * 4 + (slot & 3);
            pb1[(size_t)s * B_SZ + row] = B1;
            pb2[(size_t)s * B_SZ + row] = B2;
            pl15[(size_t)s * B_SZ + row] = ID;
        }
    }
}

/* ------- krecover (fused kmergeArg): ONE WAVE PER ROW; split-merge inline,
   fp32 argmax over winning 64-code stream, near-tie flag ------- */
__global__ __launch_bounds__(256) void krecover(const float* __restrict__ ze_a,
                                                const float* __restrict__ cb,
                                                const float* __restrict__ pb1,
                                                const float* __restrict__ pb2,
                                                const int* __restrict__ pl15,
                                                int* __restrict__ idxt,
                                                int* __restrict__ cnt,
                                                int* __restrict__ list) {
    int tid = threadIdx.x;
    int l = tid & 63;
    int gl = l & 7;
    int gj = l >> 3;
    int row = blockIdx.x * 4 + (tid >> 6);   /* wave-uniform */

    /* split merge (ex-kmergeArg, bit-identical), redundantly on all lanes */
    float best1 = pb1[row], othv = pb2[row];
    int c = pl15[row], wsn = 0;
    #pragma unroll
    for (int s2 = 1; s2 < NSPL; ++s2) {
        float b  = pb1[(size_t)s2 * B_SZ + row];
        float sb = pb2[(size_t)s2 * B_SZ + row];
        int   li = pl15[(size_t)s2 * B_SZ + row];
        float mn = fminf(best1, b);
        othv = fmaxf(fmaxf(othv, sb), mn);
        if (b > best1) { best1 = b; c = li; wsn = s2; }
    }
    int s = wsn, lc = c;

    float4 z = *(const float4*)(ze_a + (size_t)row * 32 + gl * 4);
    float zz = fmaf(z.x, z.x, fmaf(z.y, z.y, fmaf(z.z, z.z, z.w * z.w)));
    zz += __shfl_xor(zz, 1, 64);
    zz += __shfl_xor(zz, 2, 64);
    zz += __shfl_xor(zz, 4, 64);
    float zinv = 1.f / fmaxf(sqrtf(zz), 1e-12f);
    z.x *= zinv; z.y *= zinv; z.z *= zinv; z.w *= zinv;

    float best = -1e30f; int bi = 0;
    #pragma unroll
    for (int b = 0; b < CPS / 16 / 8; ++b) {       /* 8 bursts x 8 t-slots = 64 codes */
        int t = b * 8 + gj;
        int j = s * CPS + t * 16 + lc;
        float4 w = *(const float4*)(cb + (size_t)j * 32 + gl * 4);
        float w2 = fmaf(w.x, w.x, fmaf(w.y, w.y, fmaf(w.z, w.z, w.w * w.w)));
        float dt = fmaf(z.x, w.x, fmaf(z.y, w.y, fmaf(z.z, w.z, z.w * w.w)));
        w2 += __shfl_xor(w2, 1, 64); dt += __shfl_xor(dt, 1, 64);
        w2 += __shfl_xor(w2, 2, 64); dt += __shfl_xor(dt, 2, 64);
        w2 += __shfl_xor(w2, 4, 64); dt += __shfl_xor(dt, 4, 64);
        float inv = 1.f / fmaxf(sqrtf(w2), 1e-12f);
        float m = dt * inv - 0.5f * (w2 * inv * inv);
        if (m > best || (m == best && j < bi)) { best = m; bi = j; }
    }
    #pragma unroll
    for (int mk = 8; mk <= 32; mk <<= 1) {
        float ob = __shfl_xor(best, mk, 64);
        int   oi = __shfl_xor(bi, mk, 64);
        bool take = (ob > best) || (ob == best && oi < bi);
        best = take ? ob : best;
        bi   = take ? oi : bi;
    }
    if (l == 0) {
        idxt[row] = bi;
        if (best - (othv - 0.5f) < EPS_MARGIN) {   /* m-scale vs m-scale */
            int p = atomicAdd(cnt, 1);
            if (p < RESC_CAP) list[p] = row;
        }
    }
}

/* ------- exact fp32 re-argmin for flagged rows (verified R6/R8-full-scan) ------- */
__global__ __launch_bounds__(256) void krescore(const float* __restrict__ ze_a,
                                                const float* __restrict__ cb,
                                                int* __restrict__ idxt,
                                                const int* __restrict__ cnt,
                                                const int* __restrict__ list) {
    __shared__ float bvs[4];
    __shared__ int   bis[4];
    int tid = threadIdx.x;
    int wave = tid >> 6, l = tid & 63;
    int gl = l & 7;
    int gj = l >> 3;
    int n = *cnt; if (n > RESC_CAP) n = RESC_CAP;
    for (int ii = blockIdx.x; ii < n; ii += gridDim.x) {
        int row = list[ii];
        float4 z = *(const float4*)(ze_a + (size_t)row * 32 + gl * 4);
        float zz = fmaf(z.x, z.x, fmaf(z.y, z.y, fmaf(z.z, z.z, z.w * z.w)));
        zz += __shfl_xor(zz, 1, 64);
        zz += __shfl_xor(zz, 2, 64);
        zz += __shfl_xor(zz, 4, 64);
        float zinv = 1.f / fmaxf(sqrtf(zz), 1e-12f);
        z.x *= zinv; z.y *= zinv; z.z *= zinv; z.w *= zinv;

        float best = -1e30f; int bi = 0;
        int jbase = wave * 2048 + gj;
        for (int b = 0; b < 32; ++b) {
            float w2v[8], dtv[8];
            #pragma unroll
            for (int cc = 0; cc < 8; ++cc) {
                int j = jbase + (b * 8 + cc) * 8;
                float4 w = *(const float4*)(cb + (size_t)j * 32 + gl * 4);
                w2v[cc] = fmaf(w.x, w.x, fmaf(w.y, w.y, fmaf(w.z, w.z, w.w * w.w)));
                dtv[cc] = fmaf(z.x, w.x, fmaf(z.y, w.y, fmaf(z.z, w.z, z.w * w.w)));
            }
            #pragma unroll
            for (int cc = 0; cc < 8; ++cc) {
                w2v[cc] += __shfl_xor(w2v[cc], 1, 64);
                dtv[cc] += __shfl_xor(dtv[cc], 1, 64);
            }
            #pragma unroll
            for (int cc = 0; cc < 8; ++cc) {
                w2v[cc] += __shfl_xor(w2v[cc], 2, 64);
                dtv[cc] += __shfl_xor(dtv[cc], 2, 64);
            }
            #pragma unroll
            for (int cc = 0; cc < 8; ++cc) {
                w2v[cc] += __shfl_xor(w2v[cc], 4, 64);
                dtv[cc] += __shfl_xor(dtv[cc], 4, 64);
            }
            #pragma unroll
            for (int cc = 0; cc < 8; ++cc) {
                int j = jbase + (b * 8 + cc) * 8;
                float inv = 1.f / fmaxf(sqrtf(w2v[cc]), 1e-12f);
                float m = dtv[cc] * inv - 0.5f * (w2v[cc] * inv * inv);
                if (m > best || (m == best && j < bi)) { best = m; bi = j; }
            }
        }
        #pragma unroll
        for (int mk = 8; mk <= 32; mk <<= 1) {
            float ob = __shfl_xor(best, mk, 64);
            int   oi = __shfl_xor(bi, mk, 64);
            bool take = (ob > best) || (ob == best && oi < bi);
            best = take ? ob : best;
            bi   = take ? oi : bi;
        }
        if (l == 0) { bvs[wave] = best; bis[wave] = bi; }
        __syncthreads();
        if (tid == 0) {
            float B = bvs[0]; int I = bis[0];
            #pragma unroll
            for (int w2i = 1; w2i < 4; ++w2i) {
                float ob = bvs[w2i]; int oi = bis[w2i];
                if (ob > B || (ob == B && oi < I)) { B = ob; I = oi; }
            }
            idxt[row] = I;
        }
        __syncthreads();
    }
}

/* ---------------- kout (fused kfinal): out GEMM + idx write + loss partials ---------------- */
__global__ __launch_bounds__(256) void kout(const float* __restrict__ ze_a,
                                            const int* __restrict__ idxt,
                                            const float* __restrict__ cb,
                                            const float* __restrict__ out_w,
                                            const float* __restrict__ out_b,
                                            float* __restrict__ out,
                                            float* __restrict__ out_idx,
                                            float* __restrict__ lpart) {
    __shared__ float zsh[128 * EMB];
    __shared__ int ish[128];
    __shared__ float red[4];
    int tid = threadIdx.x;
    int col = blockIdx.x * 512 + tid * 2;
    size_t row0 = (size_t)blockIdx.y * 128;
    bool bx0 = (blockIdx.x == 0);
    if (tid < 128) ish[tid] = idxt[row0 + tid];
    __syncthreads();
    float sq = 0.f;
    #pragma unroll
    for (int i = 0; i < 4; ++i) {
        int flat = i * 256 + tid;      /* 0..1023 */
        int r = flat >> 3, q = flat & 7;
        float4 zv = *(const float4*)(ze_a + (row0 + r) * EMB + q * 4);
        float4 qv = *(const float4*)(cb + (size_t)ish[r] * EMB + q * 4);
        if (bx0) {
            float dx = zv.x - qv.x, dy = zv.y - qv.y, dz = zv.z - qv.z, dw = zv.w - qv.w;
            sq += (dx * dx + dy * dy) + (dz * dz + dw * dw);
        }
        float4 o;
        o.x = zv.x + (qv.x - zv.x); o.y = zv.y + (qv.y - zv.y);
        o.z = zv.z + (qv.z - zv.z); o.w = zv.w + (qv.w - zv.w);
        *(float4*)&zsh[r * EMB + q * 4] = o;
    }
    if (bx0) {
        #pragma unroll
        for (int m = 1; m <= 32; m <<= 1) sq += __shfl_xor(sq, m, 64);
        if ((tid & 63) == 0) red[tid >> 6] = sq;
    }
    float wa[32], wb[32];
    {
        const float4* wa4 = (const float4*)(out_w + (size_t)col * EMB);
        const float4* wb4 = (const float4*)(out_w + (size_t)(col + 1) * EMB);
        #pragma unroll
        for (int i = 0; i < 8; ++i) {
            float4 a = wa4[i]; wa[4*i]=a.x; wa[4*i+1]=a.y; wa[4*i+2]=a.z; wa[4*i+3]=a.w;
            float4 b = wb4[i]; wb[4*i]=b.x; wb[4*i+1]=b.y; wb[4*i+2]=b.z; wb[4*i+3]=b.w;
        }
    }
    float b0 = out_b[col], b1 = out_b[col + 1];
    __syncthreads();
    if (bx0) {
        if (tid == 0) lpart[blockIdx.y] = (red[0] + red[1]) + (red[2] + red[3]);
        if (tid < 128) out_idx[row0 + tid] = (float)ish[tid];
    }
    for (int rr = 0; rr < 128; ++rr) {
        const float4* zr4 = (const float4*)(zsh + rr * EMB);
        float a0 = b0, a1 = b1;
        #pragma unroll
        for (int q = 0; q < 8; ++q) {
            float4 z = zr4[q];
            a0 = fmaf(z.x, wa[4*q],   a0); a1 = fmaf(z.x, wb[4*q],   a1);
            a0 = fmaf(z.y, wa[4*q+1], a0); a1 = fmaf(z.y, wb[4*q+1], a1);
            a0 = fmaf(z.z, wa[4*q+2], a0); a1 = fmaf(z.z, wb[4*q+2], a1);
            a0 = fmaf(z.w, wa[4*q+3], a0); a1 = fmaf(z.w, wb[4*q+3], a1);
        }
        float2 o; o.x = a0; o.y = a1;
        *(float2*)(out + (row0 + rr) * LAT + col) = o;
    }
}

/* ---------------- losses (256 partials) ---------------- */
__global__ void kloss(const float* __restrict__ lpart, float* __restrict__ dout) {
    float v = lpart[threadIdx.x];   /* 256 threads */
    #pragma unroll
    for (int m = 1; m <= 32; m <<= 1) v += __shfl_xor(v, m, 64);
    __shared__ float tmp[4];
    if ((threadIdx.x & 63) == 0) tmp[threadIdx.x >> 6] = v;
    __syncthreads();
    if (threadIdx.x == 0) {
        float enc = ((tmp[0] + tmp[1]) + (tmp[2] + tmp[3])) / (float)(B_SZ * EMB);
        dout[OFF_LOSS] = 1.0f * enc + 0.25f * enc;
        dout[OFF_ENC]  = enc;
        dout[OFF_CB]   = enc;
    }
}

extern "C" void kernel_launch(void* const* d_in, const int* in_sizes, int n_in,
                              void* d_out, int out_size, void* d_ws, size_t ws_size,
                              hipStream_t stream) {
    const float* z_e   = (const float*)d_in[0];
    const float* in_w  = (const float*)d_in[1];
    const float* in_b  = (const float*)d_in[2];
    const float* out_w = (const float*)d_in[3];
    const float* out_b = (const float*)d_in[4];
    const float* cb    = (const float*)d_in[5];

    float* out = (float*)d_out;
    float* ws  = (float*)d_ws;
    float* pb1   = ws + WS_PB1;
    float* pb2   = ws + WS_PB2;
    int*   pl15  = (int*)(ws + WS_PL15);
    float* ze_a  = ws + WS_ZEA;
    short* znpk  = (short*)(ws + WS_ZNPK);
    short* wpk   = (short*)(ws + WS_WPK);
    int*   idxt  = (int*)(ws + WS_IDXT);
    int*   cnt   = (int*)(ws + WS_CNT);
    int*   list  = (int*)(ws + WS_LIST);
    float* lpart = ws + WS_LPART;

    knorm   <<<dim3(ZCB / 8), dim3(32, 8), 0, stream>>>(cb, wpk, cnt);
    kzeF    <<<dim3(B_SZ / 32), 256, 0, stream>>>(z_e, in_w, in_b, out + OFF_ZE, ze_a, znpk);
    kdistM  <<<dim3(B_SZ / 256, NSPL), 256, 0, stream>>>(znpk, wpk, pb1, pb2, pl15);
    krecover<<<dim3(B_SZ / 4), 256, 0, stream>>>(ze_a, cb, pb1, pb2, pl15, idxt, cnt, list);
    krescore<<<dim3(512), 256, 0, stream>>>(ze_a, cb, idxt, cnt, list);
    kout    <<<dim3(2, B_SZ / 128), 256, 0, stream>>>(ze_a, idxt, cb, out_w, out_b, out,
                                                      out + OFF_IDX, lpart);
    kloss   <<<1, 256, 0, stream>>>(lpart, out);
}

// Round 14
// 265.948 us; speedup vs baseline: 1.0192x; 1.0192x over previous
//
#include <hip/hip_runtime.h>
#include <hip/hip_bf16.h>

#define B_SZ    32768
#define LAT     1024
#define EMB     32
#define ZCB     8192
#define NSPL    8                /* code splits for kdistM: 1024 codes each */
#define CPS     (ZCB / NSPL)     /* 1024 */
#define RESC_CAP 32768
#define EPS_MARGIN 2e-4f

/* d_out float offsets: out, loss, enc, cb, idx, ze */
#define OFF_LOSS  ((size_t)B_SZ * LAT)
#define OFF_ENC   (OFF_LOSS + 1)
#define OFF_CB    (OFF_LOSS + 2)
#define OFF_IDX   (OFF_LOSS + 3)
#define OFF_ZE    (OFF_IDX + B_SZ)

/* ws float offsets */
#define WS_PB1    0                       /* NSPL*B = 262144 */
#define WS_PB2    262144
#define WS_PL15   524288                  /* 262144 ints */
#define WS_ZEA    2097152                 /* 1048576 */
#define WS_ZNPK   3145728                 /* B*64 shorts = 1048576 floats */
#define WS_WPK    4194304                 /* Z*64 shorts = 262144 floats */
#define WS_IDXT   4456448                 /* 32768 ints */
#define WS_CNT    4489216                 /* 1 int */
#define WS_LIST   4489217                 /* 32768 ints */
#define WS_LPART  4521985                 /* 256 */

typedef float  f32x4  __attribute__((ext_vector_type(4)));
typedef short  short8 __attribute__((ext_vector_type(8)));

__device__ __forceinline__ unsigned short f2bf(float x) {
    unsigned u = __float_as_uint(x);
    u += 0x7FFF + ((u >> 16) & 1);            /* round-to-nearest-even */
    return (unsigned short)(u >> 16);
}
__device__ __forceinline__ float bf2f(unsigned short h) {
    return __uint_as_float(((unsigned)h) << 16);
}

/* ---------------- codebook: normalize + split-bf16 pack; zeroes cnt ---------------- */
__global__ __launch_bounds__(256) void knorm(const float* __restrict__ cb,
                                             short* __restrict__ wpk,
                                             int* __restrict__ cnt) {
    if (blockIdx.x == 0 && threadIdx.x == 0 && threadIdx.y == 0) *cnt = 0;
    int e = threadIdx.x;
    int r = threadIdx.y;
    int row = blockIdx.x * 8 + r;
    float v = cb[row * EMB + e];
    float s = v * v;
    #pragma unroll
    for (int m = 16; m >= 1; m >>= 1) s += __shfl_xor(s, m, 64);
    float n = fmaxf(sqrtf(s), 1e-12f);
    float w = v / n;
    unsigned short h = f2bf(w);
    unsigned short l = f2bf(w - bf2f(h));
    wpk[row * 64 + e]      = (short)h;
    wpk[row * 64 + 32 + e] = (short)l;
}

/* ------- kzeF: full-K ze GEMM + bias + norm + pack, R12 kze2 GEOMETRY -------
   64 rows/block, 4 lanes/row, 8 emb/lane — staging/swizzle/inner loop identical
   to the verified R12 kze2. Chunks 0-7 -> acc0 (= old ks=0), 8-15 -> acc1
   (= old ks=1); v = (acc0+acc1)+bias and the 2-shfl norm epilogue reproduce
   the R12 kze2+kprep fp32 chains BIT-IDENTICALLY (znpk bits identical too). */
#define KZB 64
#define KZS 68
__global__ __launch_bounds__(256) void kzeF(const float* __restrict__ z_e,
                                            const float* __restrict__ in_w,
                                            const float* __restrict__ in_b,
                                            float* __restrict__ ze_out,
                                            float* __restrict__ ze_a,
                                            short* __restrict__ znpk) {
    __shared__ float zs[64 * KZS];   /* 17.4 KB */
    __shared__ float wt[KZB * 32];   /* 8 KB */
    int tid = threadIdx.x;
    size_t row0 = (size_t)blockIdx.x * 64;
    int rs = tid >> 2;        /* 0..63: row */
    int eg = tid & 3;         /* 0..3 */
    int E  = eg * 8;

    float acc0[8], acc1[8];
    #pragma unroll
    for (int j = 0; j < 8; ++j) { acc0[j] = 0.f; acc1[j] = 0.f; }

    for (int c = 0; c < 16; ++c) {
        int kb = c * KZB;
        __syncthreads();
        /* stage z tile: 64 rows x 64 cols = 1024 float4 (verified R11/R12) */
        #pragma unroll
        for (int i = 0; i < 4; ++i) {
            int t = tid + i * 256;
            int r = t >> 4, c4 = t & 15;
            float4 v = *(const float4*)(z_e + (row0 + r) * LAT + kb + c4 * 4);
            *(float4*)&zs[r * KZS + c4 * 4] = v;
        }
        /* stage w transposed + xor-swizzled (verified R2..R12) */
        #pragma unroll
        for (int i = 0; i < 2; ++i) {
            int t = tid + i * 256;
            int e = t >> 4, k4 = t & 15;
            float4 v = *(const float4*)(in_w + (size_t)e * LAT + kb + k4 * 4);
            float vv[4] = {v.x, v.y, v.z, v.w};
            #pragma unroll
            for (int j = 0; j < 4; ++j) {
                int k = k4 * 4 + j;
                wt[k * 32 + (e ^ ((k & 7) << 2))] = vv[j];
            }
        }
        __syncthreads();
        float* acc = (c < 8) ? acc0 : acc1;
        #pragma unroll 4
        for (int kq = 0; kq < KZB / 4; ++kq) {
            int k0 = kq * 4;
            float4 za = *(const float4*)&zs[rs * KZS + k0];
            float zav[4] = {za.x, za.y, za.z, za.w};
            #pragma unroll
            for (int i = 0; i < 4; ++i) {
                int k = k0 + i;
                int sw = (k & 7) << 2;
                float4 w0 = *(const float4*)&wt[k * 32 + (E ^ sw)];
                float4 w1 = *(const float4*)&wt[k * 32 + ((E + 4) ^ sw)];
                float wa[8] = {w0.x, w0.y, w0.z, w0.w, w1.x, w1.y, w1.z, w1.w};
                #pragma unroll
                for (int j = 0; j < 8; ++j)
                    acc[j] = fmaf(zav[i], wa[j], acc[j]);
            }
        }
    }

    /* epilogue = R12 kprep, bit-identical chains */
    float4 b40 = *(const float4*)(in_b + E);
    float4 b41 = *(const float4*)(in_b + E + 4);
    float bias[8] = {b40.x, b40.y, b40.z, b40.w, b41.x, b41.y, b41.z, b41.w};
    float v[8];
    #pragma unroll
    for (int j = 0; j < 8; ++j) v[j] = acc0[j] + acc1[j] + bias[j];
    float nn = 0.f;
    #pragma unroll
    for (int j = 0; j < 8; ++j) nn = fmaf(v[j], v[j], nn);
    nn += __shfl_xor(nn, 1, 64);
    nn += __shfl_xor(nn, 2, 64);
    float n = fmaxf(sqrtf(nn), 1e-12f);

    size_t row = row0 + rs;
    *(float4*)(ze_a + row * 32 + E)     = make_float4(v[0], v[1], v[2], v[3]);
    *(float4*)(ze_a + row * 32 + E + 4) = make_float4(v[4], v[5], v[6], v[7]);
    #pragma unroll
    for (int j = 0; j < 8; ++j) ze_out[row * 32 + E + j] = v[j];

    short8 hv, lv;
    #pragma unroll
    for (int j = 0; j < 8; ++j) {
        float x = v[j] / n;
        unsigned short h = f2bf(x);
        unsigned short lo = f2bf(x - bf2f(h));
        hv[j] = (short)h;
        lv[j] = (short)lo;
    }
    *(short8*)(znpk + row * 64 + E)      = hv;
    *(short8*)(znpk + row * 64 + 32 + E) = lv;
}

/* ---------------- MFMA distance: LDS-staged codes (verified R12) ---------------- */
__global__ __launch_bounds__(256) void kdistM(const short* __restrict__ znpk,
                                              const short* __restrict__ wpk,
                                              float* __restrict__ pb1,
                                              float* __restrict__ pb2,
                                              int*   __restrict__ pl15) {
    __shared__ short wch[2][128 * 64];   /* 2 x 16 KB */
    int tid = threadIdx.x;
    int wave = tid >> 6, l = tid & 63;
    int l15 = l & 15, g = l >> 4;
    size_t rowbase = (size_t)blockIdx.x * 256 + wave * 64;
    int s = blockIdx.y;

    short8 zh[4], zl[4];
    #pragma unroll
    for (int rt = 0; rt < 4; ++rt) {
        const short8* p = (const short8*)(znpk + (rowbase + rt * 16 + l15) * 64 + g * 8);
        zh[rt] = p[0];
        zl[rt] = p[4];
    }
    f32x4 zero4 = {0.f, 0.f, 0.f, 0.f};
    float bb1[16];
    #pragma unroll
    for (int i = 0; i < 16; ++i) bb1[i] = -1e30f;

    int sw = (l15 & 7) << 4;
    int bhoff = ((g * 16) ^ sw) >> 1;
    int bloff = ((64 + g * 16) ^ sw) >> 1;

    const short* wsrc = wpk + (size_t)s * CPS * 64;

    #pragma unroll
    for (int i = 0; i < 4; ++i) {
        int t = tid + i * 256;
        int code = t >> 3, slot = t & 7;
        short8 v = *(const short8*)(wsrc + (size_t)code * 64 + slot * 8);
        int doff = (slot * 16) ^ ((code & 7) << 4);
        *(short8*)&wch[0][code * 64 + (doff >> 1)] = v;
    }
    __syncthreads();

    for (int c = 0; c < 8; ++c) {
        if (c + 1 < 8) {
            const short* src = wsrc + (size_t)(c + 1) * 128 * 64;
            #pragma unroll
            for (int i = 0; i < 4; ++i) {
                int t = tid + i * 256;
                int code = t >> 3, slot = t & 7;
                short8 v = *(const short8*)(src + (size_t)code * 64 + slot * 8);
                int doff = (slot * 16) ^ ((code & 7) << 4);
                *(short8*)&wch[(c + 1) & 1][code * 64 + (doff >> 1)] = v;
            }
        }
        const short* W = &wch[c & 1][0];
        #pragma unroll
        for (int tt = 0; tt < 8; ++tt) {
            const short* rowp = W + (tt * 16 + l15) * 64;
            short8 bh = *(const short8*)(rowp + bhoff);
            short8 bl = *(const short8*)(rowp + bloff);
            #pragma unroll
            for (int rt = 0; rt < 4; ++rt) {
                f32x4 acc = __builtin_amdgcn_mfma_f32_16x16x32_bf16(zh[rt], bh, zero4, 0, 0, 0);
                acc = __builtin_amdgcn_mfma_f32_16x16x32_bf16(zl[rt], bh, acc, 0, 0, 0);
                acc = __builtin_amdgcn_mfma_f32_16x16x32_bf16(zh[rt], bl, acc, 0, 0, 0);
                #pragma unroll
                for (int r = 0; r < 4; ++r) {
                    int slot = rt * 4 + r;
                    bb1[slot] = fmaxf(bb1[slot], acc[r]);
                }
            }
        }
        __syncthreads();
    }
    #pragma unroll
    for (int slot = 0; slot < 16; ++slot) {
        float B1 = bb1[slot], B2 = -1e30f;
        int ID = l15;
        #pragma unroll
        for (int m = 1; m <= 8; m <<= 1) {
            float ob1 = __shfl_xor(B1, m, 64);
            float ob2 = __shfl_xor(B2, m, 64);
            int   oid = __shfl_xor(ID, m, 64);
            float mn = fminf(B1, ob1);
            B2 = fmaxf(fmaxf(B2, ob2), mn);
            bool take = (ob1 > B1) || (ob1 == B1 && oid < ID);
            B1 = take ? ob1 : B1;
            ID = take ? oid : ID;
        }
        if (l15 == 0) {
            size_t row = rowbase + (size_t)(slot >> 2) * 16 + g * 4 + (slot & 3);
            pb1[(size_t)s * B_SZ + row] = B1;
            pb2[(size_t)s * B_SZ + row] = B2;
            pl15[(size_t)s * B_SZ + row] = ID;
        }
    }
}

/* ------- krecover (fused kmergeArg): ONE WAVE PER ROW; split-merge inline,
   fp32 argmax over winning 64-code stream, near-tie flag (verified R13) ------- */
__global__ __launch_bounds__(256) void krecover(const float* __restrict__ ze_a,
                                                const float* __restrict__ cb,
                                                const float* __restrict__ pb1,
                                                const float* __restrict__ pb2,
                                                const int* __restrict__ pl15,
                                                int* __restrict__ idxt,
                                                int* __restrict__ cnt,
                                                int* __restrict__ list) {
    int tid = threadIdx.x;
    int l = tid & 63;
    int gl = l & 7;
    int gj = l >> 3;
    int row = blockIdx.x * 4 + (tid >> 6);   /* wave-uniform */

    float best1 = pb1[row], othv = pb2[row];
    int c = pl15[row], wsn = 0;
    #pragma unroll
    for (int s2 = 1; s2 < NSPL; ++s2) {
        float b  = pb1[(size_t)s2 * B_SZ + row];
        float sb = pb2[(size_t)s2 * B_SZ + row];
        int   li = pl15[(size_t)s2 * B_SZ + row];
        float mn = fminf(best1, b);
        othv = fmaxf(fmaxf(othv, sb), mn);
        if (b > best1) { best1 = b; c = li; wsn = s2; }
    }
    int s = wsn, lc = c;

    float4 z = *(const float4*)(ze_a + (size_t)row * 32 + gl * 4);
    float zz = fmaf(z.x, z.x, fmaf(z.y, z.y, fmaf(z.z, z.z, z.w * z.w)));
    zz += __shfl_xor(zz, 1, 64);
    zz += __shfl_xor(zz, 2, 64);
    zz += __shfl_xor(zz, 4, 64);
    float zinv = 1.f / fmaxf(sqrtf(zz), 1e-12f);
    z.x *= zinv; z.y *= zinv; z.z *= zinv; z.w *= zinv;

    float best = -1e30f; int bi = 0;
    #pragma unroll
    for (int b = 0; b < CPS / 16 / 8; ++b) {       /* 8 bursts x 8 t-slots = 64 codes */
        int t = b * 8 + gj;
        int j = s * CPS + t * 16 + lc;
        float4 w = *(const float4*)(cb + (size_t)j * 32 + gl * 4);
        float w2 = fmaf(w.x, w.x, fmaf(w.y, w.y, fmaf(w.z, w.z, w.w * w.w)));
        float dt = fmaf(z.x, w.x, fmaf(z.y, w.y, fmaf(z.z, w.z, z.w * w.w)));
        w2 += __shfl_xor(w2, 1, 64); dt += __shfl_xor(dt, 1, 64);
        w2 += __shfl_xor(w2, 2, 64); dt += __shfl_xor(dt, 2, 64);
        w2 += __shfl_xor(w2, 4, 64); dt += __shfl_xor(dt, 4, 64);
        float inv = 1.f / fmaxf(sqrtf(w2), 1e-12f);
        float m = dt * inv - 0.5f * (w2 * inv * inv);
        if (m > best || (m == best && j < bi)) { best = m; bi = j; }
    }
    #pragma unroll
    for (int mk = 8; mk <= 32; mk <<= 1) {
        float ob = __shfl_xor(best, mk, 64);
        int   oi = __shfl_xor(bi, mk, 64);
        bool take = (ob > best) || (ob == best && oi < bi);
        best = take ? ob : best;
        bi   = take ? oi : bi;
    }
    if (l == 0) {
        idxt[row] = bi;
        if (best - (othv - 0.5f) < EPS_MARGIN) {
            int p = atomicAdd(cnt, 1);
            if (p < RESC_CAP) list[p] = row;
        }
    }
}

/* ------- exact fp32 re-argmin for flagged rows (verified R6/R8-full-scan) ------- */
__global__ __launch_bounds__(256) void krescore(const float* __restrict__ ze_a,
                                                const float* __restrict__ cb,
                                                int* __restrict__ idxt,
                                                const int* __restrict__ cnt,
                                                const int* __restrict__ list) {
    __shared__ float bvs[4];
    __shared__ int   bis[4];
    int tid = threadIdx.x;
    int wave = tid >> 6, l = tid & 63;
    int gl = l & 7;
    int gj = l >> 3;
    int n = *cnt; if (n > RESC_CAP) n = RESC_CAP;
    for (int ii = blockIdx.x; ii < n; ii += gridDim.x) {
        int row = list[ii];
        float4 z = *(const float4*)(ze_a + (size_t)row * 32 + gl * 4);
        float zz = fmaf(z.x, z.x, fmaf(z.y, z.y, fmaf(z.z, z.z, z.w * z.w)));
        zz += __shfl_xor(zz, 1, 64);
        zz += __shfl_xor(zz, 2, 64);
        zz += __shfl_xor(zz, 4, 64);
        float zinv = 1.f / fmaxf(sqrtf(zz), 1e-12f);
        z.x *= zinv; z.y *= zinv; z.z *= zinv; z.w *= zinv;

        float best = -1e30f; int bi = 0;
        int jbase = wave * 2048 + gj;
        for (int b = 0; b < 32; ++b) {
            float w2v[8], dtv[8];
            #pragma unroll
            for (int cc = 0; cc < 8; ++cc) {
                int j = jbase + (b * 8 + cc) * 8;
                float4 w = *(const float4*)(cb + (size_t)j * 32 + gl * 4);
                w2v[cc] = fmaf(w.x, w.x, fmaf(w.y, w.y, fmaf(w.z, w.z, w.w * w.w)));
                dtv[cc] = fmaf(z.x, w.x, fmaf(z.y, w.y, fmaf(z.z, w.z, z.w * w.w)));
            }
            #pragma unroll
            for (int cc = 0; cc < 8; ++cc) {
                w2v[cc] += __shfl_xor(w2v[cc], 1, 64);
                dtv[cc] += __shfl_xor(dtv[cc], 1, 64);
            }
            #pragma unroll
            for (int cc = 0; cc < 8; ++cc) {
                w2v[cc] += __shfl_xor(w2v[cc], 2, 64);
                dtv[cc] += __shfl_xor(dtv[cc], 2, 64);
            }
            #pragma unroll
            for (int cc = 0; cc < 8; ++cc) {
                w2v[cc] += __shfl_xor(w2v[cc], 4, 64);
                dtv[cc] += __shfl_xor(dtv[cc], 4, 64);
            }
            #pragma unroll
            for (int cc = 0; cc < 8; ++cc) {
                int j = jbase + (b * 8 + cc) * 8;
                float inv = 1.f / fmaxf(sqrtf(w2v[cc]), 1e-12f);
                float m = dtv[cc] * inv - 0.5f * (w2v[cc] * inv * inv);
                if (m > best || (m == best && j < bi)) { best = m; bi = j; }
            }
        }
        #pragma unroll
        for (int mk = 8; mk <= 32; mk <<= 1) {
            float ob = __shfl_xor(best, mk, 64);
            int   oi = __shfl_xor(bi, mk, 64);
            bool take = (ob > best) || (ob == best && oi < bi);
            best = take ? ob : best;
            bi   = take ? oi : bi;
        }
        if (l == 0) { bvs[wave] = best; bis[wave] = bi; }
        __syncthreads();
        if (tid == 0) {
            float B = bvs[0]; int I = bis[0];
            #pragma unroll
            for (int w2i = 1; w2i < 4; ++w2i) {
                float ob = bvs[w2i]; int oi = bis[w2i];
                if (ob > B || (ob == B && oi < I)) { B = ob; I = oi; }
            }
            idxt[row] = I;
        }
        __syncthreads();
    }
}

/* ---------------- kout (fused kfinal): out GEMM + idx write + loss partials (verified R13) ---------------- */
__global__ __launch_bounds__(256) void kout(const float* __restrict__ ze_a,
                                            const int* __restrict__ idxt,
                                            const float* __restrict__ cb,
                                            const float* __restrict__ out_w,
                                            const float* __restrict__ out_b,
                                            float* __restrict__ out,
                                            float* __restrict__ out_idx,
                                            float* __restrict__ lpart) {
    __shared__ float zsh[128 * EMB];
    __shared__ int ish[128];
    __shared__ float red[4];
    int tid = threadIdx.x;
    int col = blockIdx.x * 512 + tid * 2;
    size_t row0 = (size_t)blockIdx.y * 128;
    bool bx0 = (blockIdx.x == 0);
    if (tid < 128) ish[tid] = idxt[row0 + tid];
    __syncthreads();
    float sq = 0.f;
    #pragma unroll
    for (int i = 0; i < 4; ++i) {
        int flat = i * 256 + tid;      /* 0..1023 */
        int r = flat >> 3, q = flat & 7;
        float4 zv = *(const float4*)(ze_a + (row0 + r) * EMB + q * 4);
        float4 qv = *(const float4*)(cb + (size_t)ish[r] * EMB + q * 4);
        if (bx0) {
            float dx = zv.x - qv.x, dy = zv.y - qv.y, dz = zv.z - qv.z, dw = zv.w - qv.w;
            sq += (dx * dx + dy * dy) + (dz * dz + dw * dw);
        }
        float4 o;
        o.x = zv.x + (qv.x - zv.x); o.y = zv.y + (qv.y - zv.y);
        o.z = zv.z + (qv.z - zv.z); o.w = zv.w + (qv.w - zv.w);
        *(float4*)&zsh[r * EMB + q * 4] = o;
    }
    if (bx0) {
        #pragma unroll
        for (int m = 1; m <= 32; m <<= 1) sq += __shfl_xor(sq, m, 64);
        if ((tid & 63) == 0) red[tid >> 6] = sq;
    }
    float wa[32], wb[32];
    {
        const float4* wa4 = (const float4*)(out_w + (size_t)col * EMB);
        const float4* wb4 = (const float4*)(out_w + (size_t)(col + 1) * EMB);
        #pragma unroll
        for (int i = 0; i < 8; ++i) {
            float4 a = wa4[i]; wa[4*i]=a.x; wa[4*i+1]=a.y; wa[4*i+2]=a.z; wa[4*i+3]=a.w;
            float4 b = wb4[i]; wb[4*i]=b.x; wb[4*i+1]=b.y; wb[4*i+2]=b.z; wb[4*i+3]=b.w;
        }
    }
    float b0 = out_b[col], b1 = out_b[col + 1];
    __syncthreads();
    if (bx0) {
        if (tid == 0) lpart[blockIdx.y] = (red[0] + red[1]) + (red[2] + red[3]);
        if (tid < 128) out_idx[row0 + tid] = (float)ish[tid];
    }
    for (int rr = 0; rr < 128; ++rr) {
        const float4* zr4 = (const float4*)(zsh + rr * EMB);
        float a0 = b0, a1 = b1;
        #pragma unroll
        for (int q = 0; q < 8; ++q) {
            float4 z = zr4[q];
            a0 = fmaf(z.x, wa[4*q],   a0); a1 = fmaf(z.x, wb[4*q],   a1);
            a0 = fmaf(z.y, wa[4*q+1], a0); a1 = fmaf(z.y, wb[4*q+1], a1);
            a0 = fmaf(z.z, wa[4*q+2], a0); a1 = fmaf(z.z, wb[4*q+2], a1);
            a0 = fmaf(z.w, wa[4*q+3], a0); a1 = fmaf(z.w, wb[4*q+3], a1);
        }
        float2 o; o.x = a0; o.y = a1;
        *(float2*)(out + (row0 + rr) * LAT + col) = o;
    }
}

/* ---------------- losses (256 partials) ---------------- */
__global__ void kloss(const float* __restrict__ lpart, float* __restrict__ dout) {
    float v = lpart[threadIdx.x];   /* 256 threads */
    #pragma unroll
    for (int m = 1; m <= 32; m <<= 1) v += __shfl_xor(v, m, 64);
    __shared__ float tmp[4];
    if ((threadIdx.x & 63) == 0) tmp[threadIdx.x >> 6] = v;
    __syncthreads();
    if (threadIdx.x == 0) {
        float enc = ((tmp[0] + tmp[1]) + (tmp[2] + tmp[3])) / (float)(B_SZ * EMB);
        dout[OFF_LOSS] = 1.0f * enc + 0.25f * enc;
        dout[OFF_ENC]  = enc;
        dout[OFF_CB]   = enc;
    }
}

extern "C" void kernel_launch(void* const* d_in, const int* in_sizes, int n_in,
                              void* d_out, int out_size, void* d_ws, size_t ws_size,
                              hipStream_t stream) {
    const float* z_e   = (const float*)d_in[0];
    const float* in_w  = (const float*)d_in[1];
    const float* in_b  = (const float*)d_in[2];
    const float* out_w = (const float*)d_in[3];
    const float* out_b = (const float*)d_in[4];
    const float* cb    = (const float*)d_in[5];

    float* out = (float*)d_out;
    float* ws  = (float*)d_ws;
    float* pb1   = ws + WS_PB1;
    float* pb2   = ws + WS_PB2;
    int*   pl15  = (int*)(ws + WS_PL15);
    float* ze_a  = ws + WS_ZEA;
    short* znpk  = (short*)(ws + WS_ZNPK);
    short* wpk   = (short*)(ws + WS_WPK);
    int*   idxt  = (int*)(ws + WS_IDXT);
    int*   cnt   = (int*)(ws + WS_CNT);
    int*   list  = (int*)(ws + WS_LIST);
    float* lpart = ws + WS_LPART;

    knorm   <<<dim3(ZCB / 8), dim3(32, 8), 0, stream>>>(cb, wpk, cnt);
    kzeF    <<<dim3(B_SZ / 64), 256, 0, stream>>>(z_e, in_w, in_b, out + OFF_ZE, ze_a, znpk);
    kdistM  <<<dim3(B_SZ / 256, NSPL), 256, 0, stream>>>(znpk, wpk, pb1, pb2, pl15);
    krecover<<<dim3(B_SZ / 4), 256, 0, stream>>>(ze_a, cb, pb1, pb2, pl15, idxt, cnt, list);
    krescore<<<dim3(512), 256, 0, stream>>>(ze_a, cb, idxt, cnt, list);
    kout    <<<dim3(2, B_SZ / 128), 256, 0, stream>>>(ze_a, idxt, cb, out_w, out_b, out,
                                                      out + OFF_IDX, lpart);
    kloss   <<<1, 256, 0, stream>>>(lpart, out);
}

// Round 15
// 258.632 us; speedup vs baseline: 1.0480x; 1.0283x over previous
//
#include <hip/hip_runtime.h>
#include <hip/hip_bf16.h>

#define B_SZ    32768
#define LAT     1024
#define EMB     32
#define ZCB     8192
#define NSPL    8                /* code splits for kdistM: 1024 codes each */
#define CPS     (ZCB / NSPL)     /* 1024 */
#define RESC_CAP 32768
#define EPS_MARGIN 2e-4f

/* d_out float offsets: out, loss, enc, cb, idx, ze */
#define OFF_LOSS  ((size_t)B_SZ * LAT)
#define OFF_ENC   (OFF_LOSS + 1)
#define OFF_CB    (OFF_LOSS + 2)
#define OFF_IDX   (OFF_LOSS + 3)
#define OFF_ZE    (OFF_IDX + B_SZ)

/* ws float offsets (aliased by lifetime):
   [0 .. 2097152): PZE (kze2->kprep), then PB1/PB2/PL15 (kdistM->krecover) */
#define WS_PZE    0
#define WS_PB1    0                       /* NSPL*B = 262144 */
#define WS_PB2    262144
#define WS_PL15   524288                  /* 262144 ints */
#define WS_ZEA    2097152                 /* 1048576 */
#define WS_ZNPK   3145728                 /* B*64 shorts = 1048576 floats */
#define WS_WPK    4194304                 /* Z*64 shorts = 262144 floats */
#define WS_IDXT   4456448                 /* 32768 ints */
#define WS_CNT    4489216                 /* 1 int */
#define WS_LIST   4489217                 /* 32768 ints */
#define WS_LPART  4521985                 /* 256 */

typedef float  f32x4  __attribute__((ext_vector_type(4)));
typedef short  short8 __attribute__((ext_vector_type(8)));

__device__ __forceinline__ unsigned short f2bf(float x) {
    unsigned u = __float_as_uint(x);
    u += 0x7FFF + ((u >> 16) & 1);            /* round-to-nearest-even */
    return (unsigned short)(u >> 16);
}
__device__ __forceinline__ float bf2f(unsigned short h) {
    return __uint_as_float(((unsigned)h) << 16);
}

/* ---------------- codebook: normalize + split-bf16 pack; zeroes cnt ---------------- */
__global__ __launch_bounds__(256) void knorm(const float* __restrict__ cb,
                                             short* __restrict__ wpk,
                                             int* __restrict__ cnt) {
    if (blockIdx.x == 0 && threadIdx.x == 0 && threadIdx.y == 0) *cnt = 0;
    int e = threadIdx.x;
    int r = threadIdx.y;
    int row = blockIdx.x * 8 + r;
    float v = cb[row * EMB + e];
    float s = v * v;
    #pragma unroll
    for (int m = 16; m >= 1; m >>= 1) s += __shfl_xor(s, m, 64);
    float n = fmaxf(sqrtf(s), 1e-12f);
    float w = v / n;
    unsigned short h = f2bf(w);
    unsigned short l = f2bf(w - bf2f(h));
    wpk[row * 64 + e]      = (short)h;
    wpk[row * 64 + 32 + e] = (short)l;
}

/* ---------------- ze partial GEMM: pze[ks][B][32]; 64-row tile, K-split x2
   (R12-VERBATIM — occupancy beats traffic: 1024 blocks = 16 waves/CU) ---------------- */
#define KZB 64
#define KZS 68
__global__ __launch_bounds__(256) void kze2(const float* __restrict__ z_e,
                                            const float* __restrict__ in_w,
                                            float* __restrict__ pze) {
    __shared__ float zs[64 * KZS];    /* 17.4 KB */
    __shared__ float wt[KZB * 32];    /* 8 KB */
    int tid = threadIdx.x;
    size_t row0 = (size_t)blockIdx.x * 64;
    int ks = blockIdx.y;
    int rs = tid >> 2;
    int eg = tid & 3;
    int E  = eg * 8;

    float acc[8];
    #pragma unroll
    for (int j = 0; j < 8; ++j) acc[j] = 0.f;

    for (int c = 0; c < 512 / KZB; ++c) {
        int kb = ks * 512 + c * KZB;
        __syncthreads();
        #pragma unroll
        for (int i = 0; i < 4; ++i) {
            int t = tid + i * 256;
            int r = t >> 4, c4 = t & 15;
            float4 v = *(const float4*)(z_e + (row0 + r) * LAT + kb + c4 * 4);
            *(float4*)&zs[r * KZS + c4 * 4] = v;
        }
        #pragma unroll
        for (int i = 0; i < 2; ++i) {
            int t = tid + i * 256;
            int e = t >> 4, k4 = t & 15;
            float4 v = *(const float4*)(in_w + (size_t)e * LAT + kb + k4 * 4);
            float vv[4] = {v.x, v.y, v.z, v.w};
            #pragma unroll
            for (int j = 0; j < 4; ++j) {
                int k = k4 * 4 + j;
                wt[k * 32 + (e ^ ((k & 7) << 2))] = vv[j];
            }
        }
        __syncthreads();
        #pragma unroll 4
        for (int kq = 0; kq < KZB / 4; ++kq) {
            int k0 = kq * 4;
            float4 za = *(const float4*)&zs[rs * KZS + k0];
            float zav[4] = {za.x, za.y, za.z, za.w};
            #pragma unroll
            for (int i = 0; i < 4; ++i) {
                int k = k0 + i;
                int sw = (k & 7) << 2;
                float4 w0 = *(const float4*)&wt[k * 32 + (E ^ sw)];
                float4 w1 = *(const float4*)&wt[k * 32 + ((E + 4) ^ sw)];
                float wa[8] = {w0.x, w0.y, w0.z, w0.w, w1.x, w1.y, w1.z, w1.w};
                #pragma unroll
                for (int j = 0; j < 8; ++j)
                    acc[j] = fmaf(zav[i], wa[j], acc[j]);
            }
        }
    }
    size_t rb = (size_t)ks * B_SZ + row0;
    float* p0 = pze + (rb + rs) * EMB + E;
    *(float4*)p0       = make_float4(acc[0], acc[1], acc[2], acc[3]);
    *(float4*)(p0 + 4) = make_float4(acc[4], acc[5], acc[6], acc[7]);
}

/* ------- kprep: merge K-splits + bias -> ze(d_out), ze_a, zn split-bf16 pack (R12-verbatim) ------- */
__global__ __launch_bounds__(256) void kprep(const float* __restrict__ pze,
                                             const float* __restrict__ in_b,
                                             float* __restrict__ ze_out,
                                             float* __restrict__ ze_a,
                                             short* __restrict__ znpk) {
    int tid = threadIdx.x;
    size_t row = (size_t)blockIdx.x * 64 + (tid >> 2);
    int eg = tid & 3;
    const float* p0 = pze + row * 32 + eg * 8;
    const float* p1 = p0 + (size_t)B_SZ * 32;
    float4 a0 = *(const float4*)p0, a1 = *(const float4*)(p0 + 4);
    float4 b0 = *(const float4*)p1, b1 = *(const float4*)(p1 + 4);
    float4 c0 = *(const float4*)(in_b + eg * 8), c1 = *(const float4*)(in_b + eg * 8 + 4);
    float v[8];
    v[0] = a0.x + b0.x + c0.x; v[1] = a0.y + b0.y + c0.y;
    v[2] = a0.z + b0.z + c0.z; v[3] = a0.w + b0.w + c0.w;
    v[4] = a1.x + b1.x + c1.x; v[5] = a1.y + b1.y + c1.y;
    v[6] = a1.z + b1.z + c1.z; v[7] = a1.w + b1.w + c1.w;
    float nn = 0.f;
    #pragma unroll
    for (int i = 0; i < 8; ++i) nn = fmaf(v[i], v[i], nn);
    nn += __shfl_xor(nn, 1, 64);
    nn += __shfl_xor(nn, 2, 64);
    float n = fmaxf(sqrtf(nn), 1e-12f);

    *(float4*)(ze_a + row * 32 + eg * 8)     = make_float4(v[0], v[1], v[2], v[3]);
    *(float4*)(ze_a + row * 32 + eg * 8 + 4) = make_float4(v[4], v[5], v[6], v[7]);
    #pragma unroll
    for (int i = 0; i < 8; ++i) ze_out[row * 32 + eg * 8 + i] = v[i];

    short8 hv, lv;
    #pragma unroll
    for (int i = 0; i < 8; ++i) {
        float x = v[i] / n;
        unsigned short h = f2bf(x);
        unsigned short l = f2bf(x - bf2f(h));
        hv[i] = (short)h; lv[i] = (short)l;
    }
    *(short8*)(znpk + row * 64 + eg * 8)      = hv;
    *(short8*)(znpk + row * 64 + 32 + eg * 8) = lv;
}

/* ---------------- MFMA distance: LDS-staged codes (verified R12) ---------------- */
__global__ __launch_bounds__(256) void kdistM(const short* __restrict__ znpk,
                                              const short* __restrict__ wpk,
                                              float* __restrict__ pb1,
                                              float* __restrict__ pb2,
                                              int*   __restrict__ pl15) {
    __shared__ short wch[2][128 * 64];   /* 2 x 16 KB */
    int tid = threadIdx.x;
    int wave = tid >> 6, l = tid & 63;
    int l15 = l & 15, g = l >> 4;
    size_t rowbase = (size_t)blockIdx.x * 256 + wave * 64;
    int s = blockIdx.y;

    short8 zh[4], zl[4];
    #pragma unroll
    for (int rt = 0; rt < 4; ++rt) {
        const short8* p = (const short8*)(znpk + (rowbase + rt * 16 + l15) * 64 + g * 8);
        zh[rt] = p[0];
        zl[rt] = p[4];
    }
    f32x4 zero4 = {0.f, 0.f, 0.f, 0.f};
    float bb1[16];
    #pragma unroll
    for (int i = 0; i < 16; ++i) bb1[i] = -1e30f;

    int sw = (l15 & 7) << 4;
    int bhoff = ((g * 16) ^ sw) >> 1;
    int bloff = ((64 + g * 16) ^ sw) >> 1;

    const short* wsrc = wpk + (size_t)s * CPS * 64;

    #pragma unroll
    for (int i = 0; i < 4; ++i) {
        int t = tid + i * 256;
        int code = t >> 3, slot = t & 7;
        short8 v = *(const short8*)(wsrc + (size_t)code * 64 + slot * 8);
        int doff = (slot * 16) ^ ((code & 7) << 4);
        *(short8*)&wch[0][code * 64 + (doff >> 1)] = v;
    }
    __syncthreads();

    for (int c = 0; c < 8; ++c) {
        if (c + 1 < 8) {
            const short* src = wsrc + (size_t)(c + 1) * 128 * 64;
            #pragma unroll
            for (int i = 0; i < 4; ++i) {
                int t = tid + i * 256;
                int code = t >> 3, slot = t & 7;
                short8 v = *(const short8*)(src + (size_t)code * 64 + slot * 8);
                int doff = (slot * 16) ^ ((code & 7) << 4);
                *(short8*)&wch[(c + 1) & 1][code * 64 + (doff >> 1)] = v;
            }
        }
        const short* W = &wch[c & 1][0];
        #pragma unroll
        for (int tt = 0; tt < 8; ++tt) {
            const short* rowp = W + (tt * 16 + l15) * 64;
            short8 bh = *(const short8*)(rowp + bhoff);
            short8 bl = *(const short8*)(rowp + bloff);
            #pragma unroll
            for (int rt = 0; rt < 4; ++rt) {
                f32x4 acc = __builtin_amdgcn_mfma_f32_16x16x32_bf16(zh[rt], bh, zero4, 0, 0, 0);
                acc = __builtin_amdgcn_mfma_f32_16x16x32_bf16(zl[rt], bh, acc, 0, 0, 0);
                acc = __builtin_amdgcn_mfma_f32_16x16x32_bf16(zh[rt], bl, acc, 0, 0, 0);
                #pragma unroll
                for (int r = 0; r < 4; ++r) {
                    int slot = rt * 4 + r;
                    bb1[slot] = fmaxf(bb1[slot], acc[r]);
                }
            }
        }
        __syncthreads();
    }
    #pragma unroll
    for (int slot = 0; slot < 16; ++slot) {
        float B1 = bb1[slot], B2 = -1e30f;
        int ID = l15;
        #pragma unroll
        for (int m = 1; m <= 8; m <<= 1) {
            float ob1 = __shfl_xor(B1, m, 64);
            float ob2 = __shfl_xor(B2, m, 64);
            int   oid = __shfl_xor(ID, m, 64);
            float mn = fminf(B1, ob1);
            B2 = fmaxf(fmaxf(B2, ob2), mn);
            bool take = (ob1 > B1) || (ob1 == B1 && oid < ID);
            B1 = take ? ob1 : B1;
            ID = take ? oid : ID;
        }
        if (l15 == 0) {
            size_t row = rowbase + (size_t)(slot >> 2) * 16 + g * 4 + (slot & 3);
            pb1[(size_t)s * B_SZ + row] = B1;
            pb2[(size_t)s * B_SZ + row] = B2;
            pl15[(size_t)s * B_SZ + row] = ID;
        }
    }
}

/* ------- krecover (fused kmergeArg): ONE WAVE PER ROW (verified R13/R14) ------- */
__global__ __launch_bounds__(256) void krecover(const float* __restrict__ ze_a,
                                                const float* __restrict__ cb,
                                                const float* __restrict__ pb1,
                                                const float* __restrict__ pb2,
                                                const int* __restrict__ pl15,
                                                int* __restrict__ idxt,
                                                int* __restrict__ cnt,
                                                int* __restrict__ list) {
    int tid = threadIdx.x;
    int l = tid & 63;
    int gl = l & 7;
    int gj = l >> 3;
    int row = blockIdx.x * 4 + (tid >> 6);   /* wave-uniform */

    float best1 = pb1[row], othv = pb2[row];
    int c = pl15[row], wsn = 0;
    #pragma unroll
    for (int s2 = 1; s2 < NSPL; ++s2) {
        float b  = pb1[(size_t)s2 * B_SZ + row];
        float sb = pb2[(size_t)s2 * B_SZ + row];
        int   li = pl15[(size_t)s2 * B_SZ + row];
        float mn = fminf(best1, b);
        othv = fmaxf(fmaxf(othv, sb), mn);
        if (b > best1) { best1 = b; c = li; wsn = s2; }
    }
    int s = wsn, lc = c;

    float4 z = *(const float4*)(ze_a + (size_t)row * 32 + gl * 4);
    float zz = fmaf(z.x, z.x, fmaf(z.y, z.y, fmaf(z.z, z.z, z.w * z.w)));
    zz += __shfl_xor(zz, 1, 64);
    zz += __shfl_xor(zz, 2, 64);
    zz += __shfl_xor(zz, 4, 64);
    float zinv = 1.f / fmaxf(sqrtf(zz), 1e-12f);
    z.x *= zinv; z.y *= zinv; z.z *= zinv; z.w *= zinv;

    float best = -1e30f; int bi = 0;
    #pragma unroll
    for (int b = 0; b < CPS / 16 / 8; ++b) {       /* 8 bursts x 8 t-slots = 64 codes */
        int t = b * 8 + gj;
        int j = s * CPS + t * 16 + lc;
        float4 w = *(const float4*)(cb + (size_t)j * 32 + gl * 4);
        float w2 = fmaf(w.x, w.x, fmaf(w.y, w.y, fmaf(w.z, w.z, w.w * w.w)));
        float dt = fmaf(z.x, w.x, fmaf(z.y, w.y, fmaf(z.z, w.z, z.w * w.w)));
        w2 += __shfl_xor(w2, 1, 64); dt += __shfl_xor(dt, 1, 64);
        w2 += __shfl_xor(w2, 2, 64); dt += __shfl_xor(dt, 2, 64);
        w2 += __shfl_xor(w2, 4, 64); dt += __shfl_xor(dt, 4, 64);
        float inv = 1.f / fmaxf(sqrtf(w2), 1e-12f);
        float m = dt * inv - 0.5f * (w2 * inv * inv);
        if (m > best || (m == best && j < bi)) { best = m; bi = j; }
    }
    #pragma unroll
    for (int mk = 8; mk <= 32; mk <<= 1) {
        float ob = __shfl_xor(best, mk, 64);
        int   oi = __shfl_xor(bi, mk, 64);
        bool take = (ob > best) || (ob == best && oi < bi);
        best = take ? ob : best;
        bi   = take ? oi : bi;
    }
    if (l == 0) {
        idxt[row] = bi;
        if (best - (othv - 0.5f) < EPS_MARGIN) {
            int p = atomicAdd(cnt, 1);
            if (p < RESC_CAP) list[p] = row;
        }
    }
}

/* ------- exact fp32 re-argmin for flagged rows (verified R6/R8-full-scan) ------- */
__global__ __launch_bounds__(256) void krescore(const float* __restrict__ ze_a,
                                                const float* __restrict__ cb,
                                                int* __restrict__ idxt,
                                                const int* __restrict__ cnt,
                                                const int* __restrict__ list) {
    __shared__ float bvs[4];
    __shared__ int   bis[4];
    int tid = threadIdx.x;
    int wave = tid >> 6, l = tid & 63;
    int gl = l & 7;
    int gj = l >> 3;
    int n = *cnt; if (n > RESC_CAP) n = RESC_CAP;
    for (int ii = blockIdx.x; ii < n; ii += gridDim.x) {
        int row = list[ii];
        float4 z = *(const float4*)(ze_a + (size_t)row * 32 + gl * 4);
        float zz = fmaf(z.x, z.x, fmaf(z.y, z.y, fmaf(z.z, z.z, z.w * z.w)));
        zz += __shfl_xor(zz, 1, 64);
        zz += __shfl_xor(zz, 2, 64);
        zz += __shfl_xor(zz, 4, 64);
        float zinv = 1.f / fmaxf(sqrtf(zz), 1e-12f);
        z.x *= zinv; z.y *= zinv; z.z *= zinv; z.w *= zinv;

        float best = -1e30f; int bi = 0;
        int jbase = wave * 2048 + gj;
        for (int b = 0; b < 32; ++b) {
            float w2v[8], dtv[8];
            #pragma unroll
            for (int cc = 0; cc < 8; ++cc) {
                int j = jbase + (b * 8 + cc) * 8;
                float4 w = *(const float4*)(cb + (size_t)j * 32 + gl * 4);
                w2v[cc] = fmaf(w.x, w.x, fmaf(w.y, w.y, fmaf(w.z, w.z, w.w * w.w)));
                dtv[cc] = fmaf(z.x, w.x, fmaf(z.y, w.y, fmaf(z.z, w.z, z.w * w.w)));
            }
            #pragma unroll
            for (int cc = 0; cc < 8; ++cc) {
                w2v[cc] += __shfl_xor(w2v[cc], 1, 64);
                dtv[cc] += __shfl_xor(dtv[cc], 1, 64);
            }
            #pragma unroll
            for (int cc = 0; cc < 8; ++cc) {
                w2v[cc] += __shfl_xor(w2v[cc], 2, 64);
                dtv[cc] += __shfl_xor(dtv[cc], 2, 64);
            }
            #pragma unroll
            for (int cc = 0; cc < 8; ++cc) {
                w2v[cc] += __shfl_xor(w2v[cc], 4, 64);
                dtv[cc] += __shfl_xor(dtv[cc], 4, 64);
            }
            #pragma unroll
            for (int cc = 0; cc < 8; ++cc) {
                int j = jbase + (b * 8 + cc) * 8;
                float inv = 1.f / fmaxf(sqrtf(w2v[cc]), 1e-12f);
                float m = dtv[cc] * inv - 0.5f * (w2v[cc] * inv * inv);
                if (m > best || (m == best && j < bi)) { best = m; bi = j; }
            }
        }
        #pragma unroll
        for (int mk = 8; mk <= 32; mk <<= 1) {
            float ob = __shfl_xor(best, mk, 64);
            int   oi = __shfl_xor(bi, mk, 64);
            bool take = (ob > best) || (ob == best && oi < bi);
            best = take ? ob : best;
            bi   = take ? oi : bi;
        }
        if (l == 0) { bvs[wave] = best; bis[wave] = bi; }
        __syncthreads();
        if (tid == 0) {
            float B = bvs[0]; int I = bis[0];
            #pragma unroll
            for (int w2i = 1; w2i < 4; ++w2i) {
                float ob = bvs[w2i]; int oi = bis[w2i];
                if (ob > B || (ob == B && oi < I)) { B = ob; I = oi; }
            }
            idxt[row] = I;
        }
        __syncthreads();
    }
}

/* ---------------- kout (fused kfinal): out GEMM + idx write + loss partials (verified R13/R14) ---------------- */
__global__ __launch_bounds__(256) void kout(const float* __restrict__ ze_a,
                                            const int* __restrict__ idxt,
                                            const float* __restrict__ cb,
                                            const float* __restrict__ out_w,
                                            const float* __restrict__ out_b,
                                            float* __restrict__ out,
                                            float* __restrict__ out_idx,
                                            float* __restrict__ lpart) {
    __shared__ float zsh[128 * EMB];
    __shared__ int ish[128];
    __shared__ float red[4];
    int tid = threadIdx.x;
    int col = blockIdx.x * 512 + tid * 2;
    size_t row0 = (size_t)blockIdx.y * 128;
    bool bx0 = (blockIdx.x == 0);
    if (tid < 128) ish[tid] = idxt[row0 + tid];
    __syncthreads();
    float sq = 0.f;
    #pragma unroll
    for (int i = 0; i < 4; ++i) {
        int flat = i * 256 + tid;      /* 0..1023 */
        int r = flat >> 3, q = flat & 7;
        float4 zv = *(const float4*)(ze_a + (row0 + r) * EMB + q * 4);
        float4 qv = *(const float4*)(cb + (size_t)ish[r] * EMB + q * 4);
        if (bx0) {
            float dx = zv.x - qv.x, dy = zv.y - qv.y, dz = zv.z - qv.z, dw = zv.w - qv.w;
            sq += (dx * dx + dy * dy) + (dz * dz + dw * dw);
        }
        float4 o;
        o.x = zv.x + (qv.x - zv.x); o.y = zv.y + (qv.y - zv.y);
        o.z = zv.z + (qv.z - zv.z); o.w = zv.w + (qv.w - zv.w);
        *(float4*)&zsh[r * EMB + q * 4] = o;
    }
    if (bx0) {
        #pragma unroll
        for (int m = 1; m <= 32; m <<= 1) sq += __shfl_xor(sq, m, 64);
        if ((tid & 63) == 0) red[tid >> 6] = sq;
    }
    float wa[32], wb[32];
    {
        const float4* wa4 = (const float4*)(out_w + (size_t)col * EMB);
        const float4* wb4 = (const float4*)(out_w + (size_t)(col + 1) * EMB);
        #pragma unroll
        for (int i = 0; i < 8; ++i) {
            float4 a = wa4[i]; wa[4*i]=a.x; wa[4*i+1]=a.y; wa[4*i+2]=a.z; wa[4*i+3]=a.w;
            float4 b = wb4[i]; wb[4*i]=b.x; wb[4*i+1]=b.y; wb[4*i+2]=b.z; wb[4*i+3]=b.w;
        }
    }
    float b0 = out_b[col], b1 = out_b[col + 1];
    __syncthreads();
    if (bx0) {
        if (tid == 0) lpart[blockIdx.y] = (red[0] + red[1]) + (red[2] + red[3]);
        if (tid < 128) out_idx[row0 + tid] = (float)ish[tid];
    }
    for (int rr = 0; rr < 128; ++rr) {
        const float4* zr4 = (const float4*)(zsh + rr * EMB);
        float a0 = b0, a1 = b1;
        #pragma unroll
        for (int q = 0; q < 8; ++q) {
            float4 z = zr4[q];
            a0 = fmaf(z.x, wa[4*q],   a0); a1 = fmaf(z.x, wb[4*q],   a1);
            a0 = fmaf(z.y, wa[4*q+1], a0); a1 = fmaf(z.y, wb[4*q+1], a1);
            a0 = fmaf(z.z, wa[4*q+2], a0); a1 = fmaf(z.z, wb[4*q+2], a1);
            a0 = fmaf(z.w, wa[4*q+3], a0); a1 = fmaf(z.w, wb[4*q+3], a1);
        }
        float2 o; o.x = a0; o.y = a1;
        *(float2*)(out + (row0 + rr) * LAT + col) = o;
    }
}

/* ---------------- losses (256 partials) ---------------- */
__global__ void kloss(const float* __restrict__ lpart, float* __restrict__ dout) {
    float v = lpart[threadIdx.x];   /* 256 threads */
    #pragma unroll
    for (int m = 1; m <= 32; m <<= 1) v += __shfl_xor(v, m, 64);
    __shared__ float tmp[4];
    if ((threadIdx.x & 63) == 0) tmp[threadIdx.x >> 6] = v;
    __syncthreads();
    if (threadIdx.x == 0) {
        float enc = ((tmp[0] + tmp[1]) + (tmp[2] + tmp[3])) / (float)(B_SZ * EMB);
        dout[OFF_LOSS] = 1.0f * enc + 0.25f * enc;
        dout[OFF_ENC]  = enc;
        dout[OFF_CB]   = enc;
    }
}

extern "C" void kernel_launch(void* const* d_in, const int* in_sizes, int n_in,
                              void* d_out, int out_size, void* d_ws, size_t ws_size,
                              hipStream_t stream) {
    const float* z_e   = (const float*)d_in[0];
    const float* in_w  = (const float*)d_in[1];
    const float* in_b  = (const float*)d_in[2];
    const float* out_w = (const float*)d_in[3];
    const float* out_b = (const float*)d_in[4];
    const float* cb    = (const float*)d_in[5];

    float* out = (float*)d_out;
    float* ws  = (float*)d_ws;
    float* pze   = ws + WS_PZE;
    float* pb1   = ws + WS_PB1;
    float* pb2   = ws + WS_PB2;
    int*   pl15  = (int*)(ws + WS_PL15);
    float* ze_a  = ws + WS_ZEA;
    short* znpk  = (short*)(ws + WS_ZNPK);
    short* wpk   = (short*)(ws + WS_WPK);
    int*   idxt  = (int*)(ws + WS_IDXT);
    int*   cnt   = (int*)(ws + WS_CNT);
    int*   list  = (int*)(ws + WS_LIST);
    float* lpart = ws + WS_LPART;

    knorm   <<<dim3(ZCB / 8), dim3(32, 8), 0, stream>>>(cb, wpk, cnt);
    kze2    <<<dim3(B_SZ / 64, 2), 256, 0, stream>>>(z_e, in_w, pze);
    kprep   <<<dim3(B_SZ / 64), 256, 0, stream>>>(pze, in_b, out + OFF_ZE, ze_a, znpk);
    kdistM  <<<dim3(B_SZ / 256, NSPL), 256, 0, stream>>>(znpk, wpk, pb1, pb2, pl15);
    krecover<<<dim3(B_SZ / 4), 256, 0, stream>>>(ze_a, cb, pb1, pb2, pl15, idxt, cnt, list);
    krescore<<<dim3(512), 256, 0, stream>>>(ze_a, cb, idxt, cnt, list);
    kout    <<<dim3(2, B_SZ / 128), 256, 0, stream>>>(ze_a, idxt, cb, out_w, out_b, out,
                                                      out + OFF_IDX, lpart);
    kloss   <<<1, 256, 0, stream>>>(lpart, out);
}

// Round 16
// 250.008 us; speedup vs baseline: 1.0842x; 1.0345x over previous
//
#include <hip/hip_runtime.h>
#include <hip/hip_bf16.h>

#define B_SZ    32768
#define LAT     1024
#define EMB     32
#define ZCB     8192
#define NSPL    8                /* code splits for kdistM: 1024 codes each */
#define CPS     (ZCB / NSPL)     /* 1024 */
#define RESC_CAP 32768
#define EPS_MARGIN 2e-4f

/* d_out float offsets: out, loss, enc, cb, idx, ze */
#define OFF_LOSS  ((size_t)B_SZ * LAT)
#define OFF_ENC   (OFF_LOSS + 1)
#define OFF_CB    (OFF_LOSS + 2)
#define OFF_IDX   (OFF_LOSS + 3)
#define OFF_ZE    (OFF_IDX + B_SZ)

/* ws float offsets (aliased by lifetime):
   [0 .. 2097152): PZE (kze2->kprep), then PB1/PB2/PL15 (kdistM->krecover) */
#define WS_PZE    0
#define WS_PB1    0                       /* NSPL*B = 262144 */
#define WS_PB2    262144
#define WS_PL15   524288                  /* 262144 ints */
#define WS_ZEA    2097152                 /* 1048576 */
#define WS_ZNPK   3145728                 /* B*64 shorts = 1048576 floats */
#define WS_WPK    4194304                 /* Z*64 shorts = 262144 floats */
#define WS_IDXT   4456448                 /* 32768 ints */
#define WS_CNT    4489216                 /* 1 int */
#define WS_LIST   4489217                 /* 32768 ints */
#define WS_LPART  4521985                 /* 256 */

typedef float  f32x4  __attribute__((ext_vector_type(4)));
typedef short  short8 __attribute__((ext_vector_type(8)));

__device__ __forceinline__ unsigned short f2bf(float x) {
    unsigned u = __float_as_uint(x);
    u += 0x7FFF + ((u >> 16) & 1);            /* round-to-nearest-even */
    return (unsigned short)(u >> 16);
}
__device__ __forceinline__ float bf2f(unsigned short h) {
    return __uint_as_float(((unsigned)h) << 16);
}

/* ---------------- codebook: normalize + split-bf16 pack; zeroes cnt ---------------- */
__global__ __launch_bounds__(256) void knorm(const float* __restrict__ cb,
                                             short* __restrict__ wpk,
                                             int* __restrict__ cnt) {
    if (blockIdx.x == 0 && threadIdx.x == 0 && threadIdx.y == 0) *cnt = 0;
    int e = threadIdx.x;
    int r = threadIdx.y;
    int row = blockIdx.x * 8 + r;
    float v = cb[row * EMB + e];
    float s = v * v;
    #pragma unroll
    for (int m = 16; m >= 1; m >>= 1) s += __shfl_xor(s, m, 64);
    float n = fmaxf(sqrtf(s), 1e-12f);
    float w = v / n;
    unsigned short h = f2bf(w);
    unsigned short l = f2bf(w - bf2f(h));
    wpk[row * 64 + e]      = (short)h;
    wpk[row * 64 + 32 + e] = (short)l;
}

/* ---------------- ze partial GEMM: pze[ks][B][32]; 64-row tile, K-split x2 (R12-verbatim) ---------------- */
#define KZB 64
#define KZS 68
__global__ __launch_bounds__(256) void kze2(const float* __restrict__ z_e,
                                            const float* __restrict__ in_w,
                                            float* __restrict__ pze) {
    __shared__ float zs[64 * KZS];    /* 17.4 KB */
    __shared__ float wt[KZB * 32];    /* 8 KB */
    int tid = threadIdx.x;
    size_t row0 = (size_t)blockIdx.x * 64;
    int ks = blockIdx.y;
    int rs = tid >> 2;
    int eg = tid & 3;
    int E  = eg * 8;

    float acc[8];
    #pragma unroll
    for (int j = 0; j < 8; ++j) acc[j] = 0.f;

    for (int c = 0; c < 512 / KZB; ++c) {
        int kb = ks * 512 + c * KZB;
        __syncthreads();
        #pragma unroll
        for (int i = 0; i < 4; ++i) {
            int t = tid + i * 256;
            int r = t >> 4, c4 = t & 15;
            float4 v = *(const float4*)(z_e + (row0 + r) * LAT + kb + c4 * 4);
            *(float4*)&zs[r * KZS + c4 * 4] = v;
        }
        #pragma unroll
        for (int i = 0; i < 2; ++i) {
            int t = tid + i * 256;
            int e = t >> 4, k4 = t & 15;
            float4 v = *(const float4*)(in_w + (size_t)e * LAT + kb + k4 * 4);
            float vv[4] = {v.x, v.y, v.z, v.w};
            #pragma unroll
            for (int j = 0; j < 4; ++j) {
                int k = k4 * 4 + j;
                wt[k * 32 + (e ^ ((k & 7) << 2))] = vv[j];
            }
        }
        __syncthreads();
        #pragma unroll 4
        for (int kq = 0; kq < KZB / 4; ++kq) {
            int k0 = kq * 4;
            float4 za = *(const float4*)&zs[rs * KZS + k0];
            float zav[4] = {za.x, za.y, za.z, za.w};
            #pragma unroll
            for (int i = 0; i < 4; ++i) {
                int k = k0 + i;
                int sw = (k & 7) << 2;
                float4 w0 = *(const float4*)&wt[k * 32 + (E ^ sw)];
                float4 w1 = *(const float4*)&wt[k * 32 + ((E + 4) ^ sw)];
                float wa[8] = {w0.x, w0.y, w0.z, w0.w, w1.x, w1.y, w1.z, w1.w};
                #pragma unroll
                for (int j = 0; j < 8; ++j)
                    acc[j] = fmaf(zav[i], wa[j], acc[j]);
            }
        }
    }
    size_t rb = (size_t)ks * B_SZ + row0;
    float* p0 = pze + (rb + rs) * EMB + E;
    *(float4*)p0       = make_float4(acc[0], acc[1], acc[2], acc[3]);
    *(float4*)(p0 + 4) = make_float4(acc[4], acc[5], acc[6], acc[7]);
}

/* ------- kprep: merge K-splits + bias -> ze(d_out), ze_a, zn split-bf16 pack (R12-verbatim) ------- */
__global__ __launch_bounds__(256) void kprep(const float* __restrict__ pze,
                                             const float* __restrict__ in_b,
                                             float* __restrict__ ze_out,
                                             float* __restrict__ ze_a,
                                             short* __restrict__ znpk) {
    int tid = threadIdx.x;
    size_t row = (size_t)blockIdx.x * 64 + (tid >> 2);
    int eg = tid & 3;
    const float* p0 = pze + row * 32 + eg * 8;
    const float* p1 = p0 + (size_t)B_SZ * 32;
    float4 a0 = *(const float4*)p0, a1 = *(const float4*)(p0 + 4);
    float4 b0 = *(const float4*)p1, b1 = *(const float4*)(p1 + 4);
    float4 c0 = *(const float4*)(in_b + eg * 8), c1 = *(const float4*)(in_b + eg * 8 + 4);
    float v[8];
    v[0] = a0.x + b0.x + c0.x; v[1] = a0.y + b0.y + c0.y;
    v[2] = a0.z + b0.z + c0.z; v[3] = a0.w + b0.w + c0.w;
    v[4] = a1.x + b1.x + c1.x; v[5] = a1.y + b1.y + c1.y;
    v[6] = a1.z + b1.z + c1.z; v[7] = a1.w + b1.w + c1.w;
    float nn = 0.f;
    #pragma unroll
    for (int i = 0; i < 8; ++i) nn = fmaf(v[i], v[i], nn);
    nn += __shfl_xor(nn, 1, 64);
    nn += __shfl_xor(nn, 2, 64);
    float n = fmaxf(sqrtf(nn), 1e-12f);

    *(float4*)(ze_a + row * 32 + eg * 8)     = make_float4(v[0], v[1], v[2], v[3]);
    *(float4*)(ze_a + row * 32 + eg * 8 + 4) = make_float4(v[4], v[5], v[6], v[7]);
    #pragma unroll
    for (int i = 0; i < 8; ++i) ze_out[row * 32 + eg * 8 + i] = v[i];

    short8 hv, lv;
    #pragma unroll
    for (int i = 0; i < 8; ++i) {
        float x = v[i] / n;
        unsigned short h = f2bf(x);
        unsigned short l = f2bf(x - bf2f(h));
        hv[i] = (short)h; lv[i] = (short)l;
    }
    *(short8*)(znpk + row * 64 + eg * 8)      = hv;
    *(short8*)(znpk + row * 64 + 32 + eg * 8) = lv;
}

/* ---------------- MFMA distance: LDS-staged codes via global_load_lds ----------------
   gload_lds writes LINEAR (wave-uniform base + lane*16); the XOR swizzle is moved to
   the GLOBAL source address (involution), so LDS contents are BIT-IDENTICAL to the
   verified R12 layout and the swizzled ds_read side is unchanged. */
__global__ __launch_bounds__(256) void kdistM(const short* __restrict__ znpk,
                                              const short* __restrict__ wpk,
                                              float* __restrict__ pb1,
                                              float* __restrict__ pb2,
                                              int*   __restrict__ pl15) {
    __shared__ short wch[2][128 * 64];   /* 2 x 16 KB */
    int tid = threadIdx.x;
    int wave = tid >> 6, l = tid & 63;
    int l15 = l & 15, g = l >> 4;
    size_t rowbase = (size_t)blockIdx.x * 256 + wave * 64;
    int s = blockIdx.y;

    short8 zh[4], zl[4];
    #pragma unroll
    for (int rt = 0; rt < 4; ++rt) {
        const short8* p = (const short8*)(znpk + (rowbase + rt * 16 + l15) * 64 + g * 8);
        zh[rt] = p[0];
        zl[rt] = p[4];
    }
    f32x4 zero4 = {0.f, 0.f, 0.f, 0.f};
    float bb1[16];
    #pragma unroll
    for (int i = 0; i < 16; ++i) bb1[i] = -1e30f;

    int sw = (l15 & 7) << 4;
    int bhoff = ((g * 16) ^ sw) >> 1;
    int bloff = ((64 + g * 16) ^ sw) >> 1;

    const short* wsrc = wpk + (size_t)s * CPS * 64;

    /* async stage of one 16KB chunk: wave w covers its 4KB quarter, 4 x 1KB calls.
       lane l, call i: dest (implicit) = base + l*16; source slot = (l&7)^(code&7). */
#define STAGE_CHUNK(BUF, CC)                                                          \
    {                                                                                 \
        const char* wsb = (const char*)(wsrc + (size_t)(CC) * 128 * 64);              \
        _Pragma("unroll")                                                             \
        for (int i = 0; i < 4; ++i) {                                                 \
            int code0 = wave * 32 + i * 8 + (l >> 3);                                 \
            int sslot = (l & 7) ^ (code0 & 7);                                        \
            const void* gp = (const void*)(wsb + (size_t)code0 * 128 + sslot * 16);   \
            void* lp = (void*)&wch[BUF][(wave * 4096 + i * 1024) >> 1];               \
            __builtin_amdgcn_global_load_lds(                                         \
                (const __attribute__((address_space(1))) unsigned*)gp,                \
                (__attribute__((address_space(3))) unsigned*)lp, 16, 0, 0);           \
        }                                                                             \
    }

    STAGE_CHUNK(0, 0)
    __syncthreads();

    for (int c = 0; c < 8; ++c) {
        if (c + 1 < 8) STAGE_CHUNK((c + 1) & 1, c + 1)   /* streams to LDS under MFMA */
        const short* W = &wch[c & 1][0];
        #pragma unroll
        for (int tt = 0; tt < 8; ++tt) {
            const short* rowp = W + (tt * 16 + l15) * 64;
            short8 bh = *(const short8*)(rowp + bhoff);
            short8 bl = *(const short8*)(rowp + bloff);
            #pragma unroll
            for (int rt = 0; rt < 4; ++rt) {
                f32x4 acc = __builtin_amdgcn_mfma_f32_16x16x32_bf16(zh[rt], bh, zero4, 0, 0, 0);
                acc = __builtin_amdgcn_mfma_f32_16x16x32_bf16(zl[rt], bh, acc, 0, 0, 0);
                acc = __builtin_amdgcn_mfma_f32_16x16x32_bf16(zh[rt], bl, acc, 0, 0, 0);
                #pragma unroll
                for (int r = 0; r < 4; ++r) {
                    int slot = rt * 4 + r;
                    bb1[slot] = fmaxf(bb1[slot], acc[r]);
                }
            }
        }
        __syncthreads();
    }
#undef STAGE_CHUNK
    #pragma unroll
    for (int slot = 0; slot < 16; ++slot) {
        float B1 = bb1[slot], B2 = -1e30f;
        int ID = l15;
        #pragma unroll
        for (int m = 1; m <= 8; m <<= 1) {
            float ob1 = __shfl_xor(B1, m, 64);
            float ob2 = __shfl_xor(B2, m, 64);
            int   oid = __shfl_xor(ID, m, 64);
            float mn = fminf(B1, ob1);
            B2 = fmaxf(fmaxf(B2, ob2), mn);
            bool take = (ob1 > B1) || (ob1 == B1 && oid < ID);
            B1 = take ? ob1 : B1;
            ID = take ? oid : ID;
        }
        if (l15 == 0) {
            size_t row = rowbase + (size_t)(slot >> 2) * 16 + g * 4 + (slot & 3);
            pb1[(size_t)s * B_SZ + row] = B1;
            pb2[(size_t)s * B_SZ + row] = B2;
            pl15[(size_t)s * B_SZ + row] = ID;
        }
    }
}

/* ------- krecover (fused kmergeArg): ONE WAVE PER ROW (verified R13-R15) ------- */
__global__ __launch_bounds__(256) void krecover(const float* __restrict__ ze_a,
                                                const float* __restrict__ cb,
                                                const float* __restrict__ pb1,
                                                const float* __restrict__ pb2,
                                                const int* __restrict__ pl15,
                                                int* __restrict__ idxt,
                                                int* __restrict__ cnt,
                                                int* __restrict__ list) {
    int tid = threadIdx.x;
    int l = tid & 63;
    int gl = l & 7;
    int gj = l >> 3;
    int row = blockIdx.x * 4 + (tid >> 6);   /* wave-uniform */

    float best1 = pb1[row], othv = pb2[row];
    int c = pl15[row], wsn = 0;
    #pragma unroll
    for (int s2 = 1; s2 < NSPL; ++s2) {
        float b  = pb1[(size_t)s2 * B_SZ + row];
        float sb = pb2[(size_t)s2 * B_SZ + row];
        int   li = pl15[(size_t)s2 * B_SZ + row];
        float mn = fminf(best1, b);
        othv = fmaxf(fmaxf(othv, sb), mn);
        if (b > best1) { best1 = b; c = li; wsn = s2; }
    }
    int s = wsn, lc = c;

    float4 z = *(const float4*)(ze_a + (size_t)row * 32 + gl * 4);
    float zz = fmaf(z.x, z.x, fmaf(z.y, z.y, fmaf(z.z, z.z, z.w * z.w)));
    zz += __shfl_xor(zz, 1, 64);
    zz += __shfl_xor(zz, 2, 64);
    zz += __shfl_xor(zz, 4, 64);
    float zinv = 1.f / fmaxf(sqrtf(zz), 1e-12f);
    z.x *= zinv; z.y *= zinv; z.z *= zinv; z.w *= zinv;

    float best = -1e30f; int bi = 0;
    #pragma unroll
    for (int b = 0; b < CPS / 16 / 8; ++b) {       /* 8 bursts x 8 t-slots = 64 codes */
        int t = b * 8 + gj;
        int j = s * CPS + t * 16 + lc;
        float4 w = *(const float4*)(cb + (size_t)j * 32 + gl * 4);
        float w2 = fmaf(w.x, w.x, fmaf(w.y, w.y, fmaf(w.z, w.z, w.w * w.w)));
        float dt = fmaf(z.x, w.x, fmaf(z.y, w.y, fmaf(z.z, w.z, z.w * w.w)));
        w2 += __shfl_xor(w2, 1, 64); dt += __shfl_xor(dt, 1, 64);
        w2 += __shfl_xor(w2, 2, 64); dt += __shfl_xor(dt, 2, 64);
        w2 += __shfl_xor(w2, 4, 64); dt += __shfl_xor(dt, 4, 64);
        float inv = 1.f / fmaxf(sqrtf(w2), 1e-12f);
        float m = dt * inv - 0.5f * (w2 * inv * inv);
        if (m > best || (m == best && j < bi)) { best = m; bi = j; }
    }
    #pragma unroll
    for (int mk = 8; mk <= 32; mk <<= 1) {
        float ob = __shfl_xor(best, mk, 64);
        int   oi = __shfl_xor(bi, mk, 64);
        bool take = (ob > best) || (ob == best && oi < bi);
        best = take ? ob : best;
        bi   = take ? oi : bi;
    }
    if (l == 0) {
        idxt[row] = bi;
        if (best - (othv - 0.5f) < EPS_MARGIN) {
            int p = atomicAdd(cnt, 1);
            if (p < RESC_CAP) list[p] = row;
        }
    }
}

/* ------- exact fp32 re-argmin for flagged rows (verified R6/R8-full-scan) ------- */
__global__ __launch_bounds__(256) void krescore(const float* __restrict__ ze_a,
                                                const float* __restrict__ cb,
                                                int* __restrict__ idxt,
                                                const int* __restrict__ cnt,
                                                const int* __restrict__ list) {
    __shared__ float bvs[4];
    __shared__ int   bis[4];
    int tid = threadIdx.x;
    int wave = tid >> 6, l = tid & 63;
    int gl = l & 7;
    int gj = l >> 3;
    int n = *cnt; if (n > RESC_CAP) n = RESC_CAP;
    for (int ii = blockIdx.x; ii < n; ii += gridDim.x) {
        int row = list[ii];
        float4 z = *(const float4*)(ze_a + (size_t)row * 32 + gl * 4);
        float zz = fmaf(z.x, z.x, fmaf(z.y, z.y, fmaf(z.z, z.z, z.w * z.w)));
        zz += __shfl_xor(zz, 1, 64);
        zz += __shfl_xor(zz, 2, 64);
        zz += __shfl_xor(zz, 4, 64);
        float zinv = 1.f / fmaxf(sqrtf(zz), 1e-12f);
        z.x *= zinv; z.y *= zinv; z.z *= zinv; z.w *= zinv;

        float best = -1e30f; int bi = 0;
        int jbase = wave * 2048 + gj;
        for (int b = 0; b < 32; ++b) {
            float w2v[8], dtv[8];
            #pragma unroll
            for (int cc = 0; cc < 8; ++cc) {
                int j = jbase + (b * 8 + cc) * 8;
                float4 w = *(const float4*)(cb + (size_t)j * 32 + gl * 4);
                w2v[cc] = fmaf(w.x, w.x, fmaf(w.y, w.y, fmaf(w.z, w.z, w.w * w.w)));
                dtv[cc] = fmaf(z.x, w.x, fmaf(z.y, w.y, fmaf(z.z, w.z, z.w * w.w)));
            }
            #pragma unroll
            for (int cc = 0; cc < 8; ++cc) {
                w2v[cc] += __shfl_xor(w2v[cc], 1, 64);
                dtv[cc] += __shfl_xor(dtv[cc], 1, 64);
            }
            #pragma unroll
            for (int cc = 0; cc < 8; ++cc) {
                w2v[cc] += __shfl_xor(w2v[cc], 2, 64);
                dtv[cc] += __shfl_xor(dtv[cc], 2, 64);
            }
            #pragma unroll
            for (int cc = 0; cc < 8; ++cc) {
                w2v[cc] += __shfl_xor(w2v[cc], 4, 64);
                dtv[cc] += __shfl_xor(dtv[cc], 4, 64);
            }
            #pragma unroll
            for (int cc = 0; cc < 8; ++cc) {
                int j = jbase + (b * 8 + cc) * 8;
                float inv = 1.f / fmaxf(sqrtf(w2v[cc]), 1e-12f);
                float m = dtv[cc] * inv - 0.5f * (w2v[cc] * inv * inv);
                if (m > best || (m == best && j < bi)) { best = m; bi = j; }
            }
        }
        #pragma unroll
        for (int mk = 8; mk <= 32; mk <<= 1) {
            float ob = __shfl_xor(best, mk, 64);
            int   oi = __shfl_xor(bi, mk, 64);
            bool take = (ob > best) || (ob == best && oi < bi);
            best = take ? ob : best;
            bi   = take ? oi : bi;
        }
        if (l == 0) { bvs[wave] = best; bis[wave] = bi; }
        __syncthreads();
        if (tid == 0) {
            float B = bvs[0]; int I = bis[0];
            #pragma unroll
            for (int w2i = 1; w2i < 4; ++w2i) {
                float ob = bvs[w2i]; int oi = bis[w2i];
                if (ob > B || (ob == B && oi < I)) { B = ob; I = oi; }
            }
            idxt[row] = I;
        }
        __syncthreads();
    }
}

/* ---------------- kout (fused kfinal): out GEMM + idx write + loss partials (verified R13-R15) ---------------- */
__global__ __launch_bounds__(256) void kout(const float* __restrict__ ze_a,
                                            const int* __restrict__ idxt,
                                            const float* __restrict__ cb,
                                            const float* __restrict__ out_w,
                                            const float* __restrict__ out_b,
                                            float* __restrict__ out,
                                            float* __restrict__ out_idx,
                                            float* __restrict__ lpart) {
    __shared__ float zsh[128 * EMB];
    __shared__ int ish[128];
    __shared__ float red[4];
    int tid = threadIdx.x;
    int col = blockIdx.x * 512 + tid * 2;
    size_t row0 = (size_t)blockIdx.y * 128;
    bool bx0 = (blockIdx.x == 0);
    if (tid < 128) ish[tid] = idxt[row0 + tid];
    __syncthreads();
    float sq = 0.f;
    #pragma unroll
    for (int i = 0; i < 4; ++i) {
        int flat = i * 256 + tid;      /* 0..1023 */
        int r = flat >> 3, q = flat & 7;
        float4 zv = *(const float4*)(ze_a + (row0 + r) * EMB + q * 4);
        float4 qv = *(const float4*)(cb + (size_t)ish[r] * EMB + q * 4);
        if (bx0) {
            float dx = zv.x - qv.x, dy = zv.y - qv.y, dz = zv.z - qv.z, dw = zv.w - qv.w;
            sq += (dx * dx + dy * dy) + (dz * dz + dw * dw);
        }
        float4 o;
        o.x = zv.x + (qv.x - zv.x); o.y = zv.y + (qv.y - zv.y);
        o.z = zv.z + (qv.z - zv.z); o.w = zv.w + (qv.w - zv.w);
        *(float4*)&zsh[r * EMB + q * 4] = o;
    }
    if (bx0) {
        #pragma unroll
        for (int m = 1; m <= 32; m <<= 1) sq += __shfl_xor(sq, m, 64);
        if ((tid & 63) == 0) red[tid >> 6] = sq;
    }
    float wa[32], wb[32];
    {
        const float4* wa4 = (const float4*)(out_w + (size_t)col * EMB);
        const float4* wb4 = (const float4*)(out_w + (size_t)(col + 1) * EMB);
        #pragma unroll
        for (int i = 0; i < 8; ++i) {
            float4 a = wa4[i]; wa[4*i]=a.x; wa[4*i+1]=a.y; wa[4*i+2]=a.z; wa[4*i+3]=a.w;
            float4 b = wb4[i]; wb[4*i]=b.x; wb[4*i+1]=b.y; wb[4*i+2]=b.z; wb[4*i+3]=b.w;
        }
    }
    float b0 = out_b[col], b1 = out_b[col + 1];
    __syncthreads();
    if (bx0) {
        if (tid == 0) lpart[blockIdx.y] = (red[0] + red[1]) + (red[2] + red[3]);
        if (tid < 128) out_idx[row0 + tid] = (float)ish[tid];
    }
    for (int rr = 0; rr < 128; ++rr) {
        const float4* zr4 = (const float4*)(zsh + rr * EMB);
        float a0 = b0, a1 = b1;
        #pragma unroll
        for (int q = 0; q < 8; ++q) {
            float4 z = zr4[q];
            a0 = fmaf(z.x, wa[4*q],   a0); a1 = fmaf(z.x, wb[4*q],   a1);
            a0 = fmaf(z.y, wa[4*q+1], a0); a1 = fmaf(z.y, wb[4*q+1], a1);
            a0 = fmaf(z.z, wa[4*q+2], a0); a1 = fmaf(z.z, wb[4*q+2], a1);
            a0 = fmaf(z.w, wa[4*q+3], a0); a1 = fmaf(z.w, wb[4*q+3], a1);
        }
        float2 o; o.x = a0; o.y = a1;
        *(float2*)(out + (row0 + rr) * LAT + col) = o;
    }
}

/* ---------------- losses (256 partials) ---------------- */
__global__ void kloss(const float* __restrict__ lpart, float* __restrict__ dout) {
    float v = lpart[threadIdx.x];   /* 256 threads */
    #pragma unroll
    for (int m = 1; m <= 32; m <<= 1) v += __shfl_xor(v, m, 64);
    __shared__ float tmp[4];
    if ((threadIdx.x & 63) == 0) tmp[threadIdx.x >> 6] = v;
    __syncthreads();
    if (threadIdx.x == 0) {
        float enc = ((tmp[0] + tmp[1]) + (tmp[2] + tmp[3])) / (float)(B_SZ * EMB);
        dout[OFF_LOSS] = 1.0f * enc + 0.25f * enc;
        dout[OFF_ENC]  = enc;
        dout[OFF_CB]   = enc;
    }
}

extern "C" void kernel_launch(void* const* d_in, const int* in_sizes, int n_in,
                              void* d_out, int out_size, void* d_ws, size_t ws_size,
                              hipStream_t stream) {
    const float* z_e   = (const float*)d_in[0];
    const float* in_w  = (const float*)d_in[1];
    const float* in_b  = (const float*)d_in[2];
    const float* out_w = (const float*)d_in[3];
    const float* out_b = (const float*)d_in[4];
    const float* cb    = (const float*)d_in[5];

    float* out = (float*)d_out;
    float* ws  = (float*)d_ws;
    float* pze   = ws + WS_PZE;
    float* pb1   = ws + WS_PB1;
    float* pb2   = ws + WS_PB2;
    int*   pl15  = (int*)(ws + WS_PL15);
    float* ze_a  = ws + WS_ZEA;
    short* znpk  = (short*)(ws + WS_ZNPK);
    short* wpk   = (short*)(ws + WS_WPK);
    int*   idxt  = (int*)(ws + WS_IDXT);
    int*   cnt   = (int*)(ws + WS_CNT);
    int*   list  = (int*)(ws + WS_LIST);
    float* lpart = ws + WS_LPART;

    knorm   <<<dim3(ZCB / 8), dim3(32, 8), 0, stream>>>(cb, wpk, cnt);
    kze2    <<<dim3(B_SZ / 64, 2), 256, 0, stream>>>(z_e, in_w, pze);
    kprep   <<<dim3(B_SZ / 64), 256, 0, stream>>>(pze, in_b, out + OFF_ZE, ze_a, znpk);
    kdistM  <<<dim3(B_SZ / 256, NSPL), 256, 0, stream>>>(znpk, wpk, pb1, pb2, pl15);
    krecover<<<dim3(B_SZ / 4), 256, 0, stream>>>(ze_a, cb, pb1, pb2, pl15, idxt, cnt, list);
    krescore<<<dim3(512), 256, 0, stream>>>(ze_a, cb, idxt, cnt, list);
    kout    <<<dim3(2, B_SZ / 128), 256, 0, stream>>>(ze_a, idxt, cb, out_w, out_b, out,
                                                      out + OFF_IDX, lpart);
    kloss   <<<1, 256, 0, stream>>>(lpart, out);
}